// Round 10
// baseline (669.754 us; speedup 1.0000x reference)
//
#include <hip/hip_runtime.h>
#include <hip/hip_cooperative_groups.h>

#define DIM 256
#define N_REL 8

typedef __attribute__((ext_vector_type(8))) short short8_t;
typedef __attribute__((ext_vector_type(4))) float float4_t;

// ---------------- bf16 helpers (manual, RNE) ----------------
__device__ inline unsigned short f2bf(float f) {
    unsigned u = __float_as_uint(f);
    u += 0x7FFFu + ((u >> 16) & 1u);
    return (unsigned short)(u >> 16);
}
__device__ inline float bf2f(unsigned short h) {
    return __uint_as_float(((unsigned)h) << 16);
}

// ---------------------------------------------------------------------------
// R15 fused cooperative prep+CSR kernel. 256 blocks x 256 threads (1
// block/CU -> co-residency trivially satisfiable). Collapses 9 dispatches
// {prep, memset, build, scanA, scanB, scatter, bucket, scanA2, scanB2} into
// one, removing ~8 dispatch boundaries (~7us each measured as the persistent
// "gap" across rounds). Phase logic is verbatim from the R13-verified
// kernels; grid.sync() between dependent phases.
// Key u64 = [dst:16 @bit32][et:16 @bit16][src:16 @bit0]; low u32 = ep format.
// ep order within a bucket varies run-to-run (LDS-atomic ranks) -- safe:
// aggregate sums in fp64 (order-independent, R11-verified).
// e0/e1 transients alias the yall region (dead before the first GEMM).
// ---------------------------------------------------------------------------
__global__ __launch_bounds__(256) void fused_prep_csr(
    const float* __restrict__ x, unsigned short* __restrict__ xb, int n4,
    const float* __restrict__ W0, unsigned short* __restrict__ Wt0,
    const float* __restrict__ W1, unsigned short* __restrict__ Wt1,
    const int* __restrict__ src, const int* __restrict__ dstp,
    const int* __restrict__ et, int E,
    int* __restrict__ hist, int* __restrict__ bsum,
    unsigned long long* __restrict__ e0, unsigned long long* __restrict__ e1,
    unsigned* __restrict__ ep, int* __restrict__ cnt,
    int* __restrict__ rowptr, int M)
{
    __shared__ __align__(16) int sarena[1088];   // 4352B: 32x33 f32 tile / 4x256 ints
    const int t = threadIdx.x, b = blockIdx.x;   // grid = 256

    // ---- P0a: cast x -> bf16 (grid-stride) ----
    for (int i = b * 256 + t; i < n4; i += 65536) {
        const float4 v = ((const float4*)x)[i];
        ushort4 o;
        o.x = f2bf(v.x); o.y = f2bf(v.y); o.z = f2bf(v.z); o.w = f2bf(v.w);
        ((ushort4*)xb)[i] = o;
    }
    // ---- P0b: W transposes (1024 tile jobs, exactly 4 per block) ----
    {
        float (*tile)[33] = (float(*)[33])sarena;
        const int tx = t & 31, ty = t >> 5;
        for (int job = b; job < 1024; job += 256) {
            const float* W = (job < 512) ? W0 : W1;
            unsigned short* Wt = (job < 512) ? Wt0 : Wt1;
            const int bb = job & 511;
            const int rel = bb >> 6;
            const int bx = bb & 7, by = (bb >> 3) & 7;
            const int i0 = bx * 32, o0 = by * 32;
            const float* Wr = W + (size_t)rel * DIM * DIM;
            unsigned short* Wtr = Wt + (size_t)rel * DIM * DIM;
            __syncthreads();
#pragma unroll
            for (int j = 0; j < 4; j++)
                tile[ty + 8 * j][tx] = Wr[(size_t)(i0 + ty + 8 * j) * DIM + o0 + tx];
            __syncthreads();
#pragma unroll
            for (int j = 0; j < 4; j++)
                Wtr[(size_t)(o0 + ty + 8 * j) * DIM + i0 + tx] =
                    f2bf(tile[tx][ty + 8 * j]);
        }
    }
    // ---- P1: pack keys + per-block hist of dst>>8 ----
    {
        int* lh = sarena;
        __syncthreads();
        lh[t] = 0;
        __syncthreads();
        const int chunk = (E + 255) >> 8;
        const int lo = b * chunk, hi = min(lo + chunk, E);
        for (int i = lo + t; i < hi; i += 256) {
            const unsigned d = (unsigned)dstp[i];
            e0[i] = ((unsigned long long)d << 32) |
                    ((unsigned)((et[i] << 16) | src[i]));
            atomicAdd(&lh[d >> 8], 1);
        }
        __syncthreads();
        hist[t * 256 + b] = lh[t];
    }
    cooperative_groups::this_grid().sync();
    // ---- P2: exclusive scan hist[65536] in place ----
    int myexcl;
    {
        int* sh = sarena;
        const int v = hist[b * 256 + t];
        __syncthreads();
        sh[t] = v;
        __syncthreads();
        for (int off = 1; off < 256; off <<= 1) {
            const int add = (t >= off) ? sh[t - off] : 0;
            __syncthreads();
            sh[t] += add;
            __syncthreads();
        }
        if (t == 255) bsum[b] = sh[255];
        myexcl = sh[t] - v;
    }
    cooperative_groups::this_grid().sync();
    {
        int* sb = sarena;
        __syncthreads();
        sb[t] = bsum[t];
        __syncthreads();
        for (int off = 1; off < 256; off <<= 1) {
            const int add = (t >= off) ? sb[t - off] : 0;
            __syncthreads();
            sb[t] += add;
            __syncthreads();
        }
        const int pre = (b == 0) ? 0 : sb[b - 1];
        hist[b * 256 + t] = pre + myexcl;
    }
    cooperative_groups::this_grid().sync();
    // ---- P3: scatter into 256 dst-high buckets ----
    {
        int* lbase = sarena;
        int* lrun = sarena + 256;
        __syncthreads();
        lbase[t] = hist[t * 256 + b];
        lrun[t] = 0;
        __syncthreads();
        const int chunk = (E + 255) >> 8;
        const int lo = b * chunk, hi = min(lo + chunk, E);
        for (int i = lo + t; i < hi; i += 256) {
            const unsigned long long v = e0[i];
            const int bin = (int)(v >> 40) & 0xFF;
            const int pos = lbase[bin] + atomicAdd(&lrun[bin], 1);
            e1[pos] = v;
        }
    }
    cooperative_groups::this_grid().sync();
    // ---- P4: per-bucket counting sort on dst low byte -> ep, cnt ----
    // cnt ALWAYS written (incl. zeros) -> no separate memset dispatch.
    {
        int* lh = sarena;
        int* lincl = sarena + 256;
        int* lexcl = sarena + 512;
        int* lrun = sarena + 768;
        const int start = hist[b * 256];
        const int end = (b == 255) ? E : hist[(b + 1) * 256];
        __syncthreads();
        lh[t] = 0;
        __syncthreads();
        for (int i = start + t; i < end; i += 256)
            atomicAdd(&lh[(int)(e1[i] >> 32) & 0xFF], 1);
        __syncthreads();
        const int v = lh[t];
        lincl[t] = v;
        __syncthreads();
        for (int off = 1; off < 256; off <<= 1) {
            const int add = (t >= off) ? lincl[t - off] : 0;
            __syncthreads();
            lincl[t] += add;
            __syncthreads();
        }
        lexcl[t] = lincl[t] - v;
        lrun[t] = 0;
        const int d = (b << 8) | t;
        if (d < M) cnt[d] = v;
        __syncthreads();
        for (int i = start + t; i < end; i += 256) {
            const unsigned long long xk = e1[i];
            const int low = (int)(xk >> 32) & 0xFF;
            const int pos = lexcl[low] + atomicAdd(&lrun[low], 1);
            ep[start + pos] = (unsigned)(xk & 0xFFFFFFFFu);
        }
    }
    cooperative_groups::this_grid().sync();
    // ---- P5: exclusive scan cnt[M] -> rowptr; rowptr[M] = E ----
    {
        int* s5 = sarena;
        const int c2 = (M + 255) >> 8;            // <=256 since M<65536
        const int idx = b * c2 + t;
        const int v5 = (t < c2 && idx < M) ? cnt[idx] : 0;
        __syncthreads();
        s5[t] = v5;
        __syncthreads();
        for (int off = 1; off < 256; off <<= 1) {
            const int add = (t >= off) ? s5[t - off] : 0;
            __syncthreads();
            s5[t] += add;
            __syncthreads();
        }
        if (t == 255) bsum[b] = s5[255];
        const int excl5 = s5[t] - v5;
        cooperative_groups::this_grid().sync();
        __syncthreads();
        s5[t] = bsum[t];
        __syncthreads();
        for (int off = 1; off < 256; off <<= 1) {
            const int add = (t >= off) ? s5[t - off] : 0;
            __syncthreads();
            s5[t] += add;
            __syncthreads();
        }
        const int pre5 = (b == 0) ? 0 : s5[b - 1];
        if (t < c2 && idx < M) rowptr[idx] = pre5 + excl5;
        if (b == 255 && t == 0) rowptr[M] = E;
    }
}

// ---------------------------------------------------------------------------
// Yall[rel][M][256] = relu(Xb @ W[rel] + bias) in bf16.  [R13-verified]
// Tile 128x128, BK=32, 4 waves of 64x64 (4x4 mfma_f32_16x16x32_bf16).
// global_load_lds width=16, XOR seg swizzle on BOTH sides (rule 21),
// 2-buffer vmcnt(4) schedule, R9 2-round epilogue.
// R14 lesson: MALL (L3) is read-allocate -- GEMM writebacks stream to HBM,
// so the aggregate's gather always cold-misses; yall locality schemes can't
// help. Aggregate ~83us/layer is the dataflow floor.
// ---------------------------------------------------------------------------
__global__ __launch_bounds__(256) void gemm_mfma_bias_relu(
    const unsigned short* __restrict__ Xb,    // [M][256]
    const unsigned short* __restrict__ Wtb,   // [R][256out][256in]
    const float* __restrict__ bias,           // [256]
    unsigned short* __restrict__ Yall, int M, int Rtiles)
{
    __shared__ __align__(16) short smem[16384];   // 32 KiB, 2 buffers

    const unsigned L = blockIdx.x;
    const int xcd = L & 7;
    const unsigned g = L >> 3;
    const int combo = g & 15;                 // (ntile, rel)
    const int rt = (int)((g >> 4) << 3) | xcd;
    if (rt >= Rtiles) return;
    const int m0 = rt * 128;
    const int n0 = (combo & 1) * 128;
    const int rel = combo >> 1;

    const unsigned short* Wt = Wtb + (size_t)rel * DIM * DIM;
    unsigned short* Y = Yall + (size_t)rel * M * DIM;

    const int t = threadIdx.x;
    const int lane = t & 63;
    const int w = t >> 6;
    const int wr = w & 1, wc = w >> 1;
    const int r = lane & 15, q = lane >> 4;

    const int sl = lane & 3;
    const int rsub = lane >> 2;
    const unsigned short* gA[2];
    const unsigned short* gB[2];
#pragma unroll
    for (int h = 0; h < 2; h++) {
        const int row = h * 64 + w * 16 + rsub;
        const int gseg = sl ^ ((row >> 1) & 3);          // pre-swizzled source
        gA[h] = Xb + (size_t)(m0 + row) * DIM + gseg * 8;
        gB[h] = Wt + (size_t)(n0 + row) * DIM + gseg * 8;
    }

    const int swz = (q ^ ((r >> 1) & 3)) * 8;
    int offA[4], offB[4];
#pragma unroll
    for (int mi = 0; mi < 4; mi++)
        offA[mi] = (wr * 64 + mi * 16 + r) * 32 + swz;
#pragma unroll
    for (int ni = 0; ni < 4; ni++)
        offB[ni] = (wc * 64 + ni * 16 + r) * 32 + swz;

    float4_t acc[4][4];
#pragma unroll
    for (int i = 0; i < 4; i++)
#pragma unroll
        for (int j = 0; j < 4; j++) {
            float4_t z = {0.f, 0.f, 0.f, 0.f};
            acc[i][j] = z;
        }

#define STAGE(ks, bsel)                                                         \
    {                                                                           \
        const int k0_ = (ks) * 32;                                              \
        short* Ad_ = smem + ((bsel) ? 8192 : 0);                                \
        short* Bd_ = Ad_ + 4096;                                                \
        _Pragma("unroll")                                                       \
        for (int h = 0; h < 2; h++) {                                           \
            __builtin_amdgcn_global_load_lds(                                   \
                (const __attribute__((address_space(1))) unsigned int*)(gA[h] + k0_), \
                (__attribute__((address_space(3))) unsigned int*)(Ad_ + h * 2048 + w * 512), \
                16, 0, 0);                                                      \
            __builtin_amdgcn_global_load_lds(                                   \
                (const __attribute__((address_space(1))) unsigned int*)(gB[h] + k0_), \
                (__attribute__((address_space(3))) unsigned int*)(Bd_ + h * 2048 + w * 512), \
                16, 0, 0);                                                      \
        }                                                                       \
    }

    STAGE(0, 0);
#pragma unroll 1
    for (int ks = 0; ks < 8; ks++) {
        const int cur = ks & 1;
        if (ks < 7) {
            STAGE(ks + 1, cur ^ 1);
            asm volatile("s_waitcnt vmcnt(4)" ::: "memory");
        } else {
            asm volatile("s_waitcnt vmcnt(0)" ::: "memory");
        }
        asm volatile("s_barrier" ::: "memory");

        const short* As_b = smem + (cur ? 8192 : 0);
        const short* Bs_b = As_b + 4096;
        short8_t af[4], bf[4];
#pragma unroll
        for (int mi = 0; mi < 4; mi++)
            af[mi] = *(const short8_t*)&As_b[offA[mi]];
#pragma unroll
        for (int ni = 0; ni < 4; ni++)
            bf[ni] = *(const short8_t*)&Bs_b[offB[ni]];
#pragma unroll
        for (int mi = 0; mi < 4; mi++)
#pragma unroll
            for (int ni = 0; ni < 4; ni++)
                acc[mi][ni] = __builtin_amdgcn_mfma_f32_16x16x32_bf16(
                    af[mi], bf[ni], acc[mi][ni], 0, 0, 0);
        asm volatile("s_barrier" ::: "memory");
    }
#undef STAGE

    // ---- epilogue: bias+relu, LDS-staged coalesced bf16 stores (2 rounds) ----
    short* St = smem;

    float bv[4];
#pragma unroll
    for (int ni = 0; ni < 4; ni++)
        bv[ni] = bias[n0 + wc * 64 + ni * 16 + r];

#pragma unroll
    for (int mp = 0; mp < 2; mp++) {
#pragma unroll
        for (int s = 0; s < 2; s++) {
#pragma unroll
            for (int ni = 0; ni < 4; ni++) {
#pragma unroll
                for (int e = 0; e < 4; e++) {
                    const int rl = s * 32 + wr * 16 + q * 4 + e;
                    const int col = wc * 64 + ni * 16 + r;
                    St[rl * 136 + col] =
                        f2bf(fmaxf(acc[mp * 2 + s][ni][e] + bv[ni], 0.f));
                }
            }
        }
        __syncthreads();
#pragma unroll
        for (int j = 0; j < 4; j++) {
            const int id = t + 256 * j;
            const int rl2 = id >> 4;
            const int ch = id & 15;
            const int s = rl2 >> 5;
            const int rl = rl2 & 31;
            const int grow = m0 + (rl >> 4) * 64 + (mp * 2 + s) * 16 + (rl & 15);
            const short8_t v = *(const short8_t*)&St[rl2 * 136 + ch * 8];
            if (grow < M)
                *(short8_t*)&Y[(size_t)grow * DIM + n0 + ch * 8] = v;
        }
        if (mp == 0) __syncthreads();
    }
}

// -------- aggregate: one dst per HALF-WAVE, fp64 accumulators [R13] --------
// fp64 sums are order-independent (~2^-53 rel) -> replay-deterministic under
// run-varying ep order. FETCH 247MB = unique yall re-read from HBM at ~47%
// random-512B efficiency -- the dataflow floor (R9/R10/R14 all null).
template <typename OT>
__global__ __launch_bounds__(256) void aggregate2x(
    const unsigned short* __restrict__ yall,   // [R][M][256]
    const unsigned* __restrict__ ep, const int* __restrict__ rowptr,
    OT* __restrict__ out, int M)
{
    const int lane = threadIdx.x & 63;
    const int half = lane >> 5;     // which dst of the pair
    const int cl = lane & 31;       // 16B chunk within message row
    const int wv = (blockIdx.x * blockDim.x + threadIdx.x) >> 6;
    const int nw = (gridDim.x * blockDim.x) >> 6;
    const size_t plane = (size_t)M * DIM;
    const int npair = (M + 1) >> 1;

    for (int pr = wv; pr < npair; pr += nw) {
        const int d = 2 * pr + half;
        const bool live = (d < M);
        double acc[8];
#pragma unroll
        for (int j = 0; j < 8; j++) acc[j] = 0.0;

        int beg = 0, end = 0;
        if (live) { beg = rowptr[d]; end = rowptr[d + 1]; }

        for (int c0 = beg; c0 < end; c0 += 32) {
            const int n = min(32, end - c0);
            const unsigned myep = (c0 + cl < end) ? ep[c0 + cl] : 0u;
            for (int i = 0; i < n; i += 4) {
                short8_t u[4];
#pragma unroll
                for (int j = 0; j < 4; j++) {
                    const unsigned p = __shfl(myep, half * 32 + ((i + j) & 31));
                    u[j] = *(const short8_t*)(
                        yall + (size_t)(p >> 16) * plane +
                        (size_t)(p & 0xFFFFu) * DIM + cl * 8);
                }
#pragma unroll
                for (int j = 0; j < 4; j++) {
                    if (i + j < n) {
#pragma unroll
                        for (int k = 0; k < 8; k++)
                            acc[k] += (double)bf2f((unsigned short)u[j][k]);
                    }
                }
            }
        }
        if (live) {
            OT* dp = out + (size_t)d * DIM + cl * 8;
            if (sizeof(OT) == 4) {
                *(float4*)((float*)dp) = make_float4(
                    (float)acc[0], (float)acc[1], (float)acc[2], (float)acc[3]);
                *(float4*)((float*)dp + 4) = make_float4(
                    (float)acc[4], (float)acc[5], (float)acc[6], (float)acc[7]);
            } else {
                short8_t v;
#pragma unroll
                for (int j = 0; j < 8; j++) v[j] = (short)f2bf((float)acc[j]);
                *(short8_t*)((unsigned short*)dp) = v;
            }
        }
    }
}

// ---------------- fallback: fp32 vector GEMM + atomic scatter ----------------
__global__ __launch_bounds__(256) void gemm_bias_relu_f32(
    const float* __restrict__ A, const float* __restrict__ B,
    const float* __restrict__ bias, float* __restrict__ Y, int M)
{
    __shared__ float Asf[16][132];
    __shared__ float Bsf[16][128];
    const int t = threadIdx.x;
    const int tx = t & 15, ty = t >> 4;
    const int row0 = blockIdx.x * 128, col0 = blockIdx.y * 128;
    float acc[8][8];
#pragma unroll
    for (int i = 0; i < 8; i++)
#pragma unroll
        for (int j = 0; j < 8; j++) acc[i][j] = 0.f;
    const int arow = t >> 2, akseg = (t & 3) * 4;
    const int bk0 = t >> 5, bcol = (t & 31) * 4;
    for (int k0 = 0; k0 < DIM; k0 += 16) {
#pragma unroll
        for (int h = 0; h < 2; h++) {
            const int row = row0 + arow + h * 64;
            float4 av = (row < M) ? *(const float4*)(A + (size_t)row * DIM + k0 + akseg)
                                  : make_float4(0, 0, 0, 0);
            Asf[akseg + 0][arow + h * 64] = av.x;
            Asf[akseg + 1][arow + h * 64] = av.y;
            Asf[akseg + 2][arow + h * 64] = av.z;
            Asf[akseg + 3][arow + h * 64] = av.w;
        }
#pragma unroll
        for (int h = 0; h < 2; h++) {
            const int krow = bk0 + h * 8;
            *(float4*)&Bsf[krow][bcol] =
                *(const float4*)(B + (size_t)(k0 + krow) * DIM + col0 + bcol);
        }
        __syncthreads();
#pragma unroll
        for (int k = 0; k < 16; k++) {
            float a[8], bvv[8];
            *(float4*)&a[0] = *(const float4*)&Asf[k][ty * 4];
            *(float4*)&a[4] = *(const float4*)&Asf[k][64 + ty * 4];
            *(float4*)&bvv[0] = *(const float4*)&Bsf[k][tx * 4];
            *(float4*)&bvv[4] = *(const float4*)&Bsf[k][64 + tx * 4];
#pragma unroll
            for (int i = 0; i < 8; i++)
#pragma unroll
                for (int j = 0; j < 8; j++) acc[i][j] = fmaf(a[i], bvv[j], acc[i][j]);
        }
        __syncthreads();
    }
#pragma unroll
    for (int im = 0; im < 2; im++)
#pragma unroll
        for (int i = 0; i < 4; i++) {
            const int row = row0 + im * 64 + ty * 4 + i;
            if (row >= M) continue;
#pragma unroll
            for (int jm = 0; jm < 2; jm++) {
                const int col = col0 + jm * 64 + tx * 4;
                const float4 bb = *(const float4*)(bias + col);
                float4 o;
                o.x = fmaxf(acc[im * 4 + i][jm * 4 + 0] + bb.x, 0.f);
                o.y = fmaxf(acc[im * 4 + i][jm * 4 + 1] + bb.y, 0.f);
                o.z = fmaxf(acc[im * 4 + i][jm * 4 + 2] + bb.z, 0.f);
                o.w = fmaxf(acc[im * 4 + i][jm * 4 + 3] + bb.w, 0.f);
                *(float4*)(Y + (size_t)row * DIM + col) = o;
            }
        }
}

__global__ __launch_bounds__(256) void scatter_rel(
    const float* __restrict__ y, const int* __restrict__ src,
    const int* __restrict__ dst, const int* __restrict__ et,
    int rel, float* __restrict__ out, int n_edges)
{
    const int lane = threadIdx.x & 63;
    const int wave = (blockIdx.x * blockDim.x + threadIdx.x) >> 6;
    const int nwaves = (gridDim.x * blockDim.x) >> 6;
    for (int e = wave; e < n_edges; e += nwaves) {
        if (et[e] != rel) continue;
        const float4 v = *(const float4*)(y + (size_t)src[e] * DIM + lane * 4);
        float* o = out + (size_t)dst[e] * DIM + lane * 4;
        atomicAdd(o + 0, v.x);
        atomicAdd(o + 1, v.y);
        atomicAdd(o + 2, v.z);
        atomicAdd(o + 3, v.w);
    }
}

static inline size_t align16(size_t x) { return (x + 15) & ~(size_t)15; }

extern "C" void kernel_launch(void* const* d_in, const int* in_sizes, int n_in,
                              void* d_out, int out_size, void* d_ws, size_t ws_size,
                              hipStream_t stream)
{
    const float* x  = (const float*)d_in[0];
    const float* W0 = (const float*)d_in[1];
    const float* b0 = (const float*)d_in[2];
    const float* W1 = (const float*)d_in[3];
    const float* b1 = (const float*)d_in[4];
    const int* eidx = (const int*)d_in[5];
    const int* etyp = (const int*)d_in[6];

    const int M = in_sizes[0] / DIM;   // 50000
    const int E = in_sizes[6];         // 800000
    const int* src = eidx;
    const int* dst = eidx + E;
    float* out = (float*)d_out;

    const size_t plane = (size_t)M * DIM;
    const size_t wbytes = (size_t)N_REL * DIM * DIM * 2;
    const size_t yall_bytes = (size_t)N_REL * plane * 2;   // 204.8MB

    const size_t need = align16(plane * 2)              // h1b
                      + align16(plane * 2)              // xb
                      + 2 * align16(wbytes)             // Wt0b, Wt1b
                      + align16((size_t)(M + 1) * 4)    // rowptr
                      + align16((size_t)M * 4)          // cnt
                      + align16((size_t)256 * 4)        // bsum
                      + align16((size_t)256 * 256 * 4)  // hist (256KB)
                      + align16((size_t)E * 4)          // ep
                      + align16(yall_bytes);            // yall (e64a/b alias)

    if (M < 65536 && ws_size >= need && yall_bytes >= 2 * (size_t)E * 8) {
        char* ws = (char*)d_ws;
        size_t off = 0;
        unsigned short* h1b  = (unsigned short*)(ws + off); off = align16(off + plane * 2);
        unsigned short* xb   = (unsigned short*)(ws + off); off = align16(off + plane * 2);
        unsigned short* Wt0b = (unsigned short*)(ws + off); off = align16(off + wbytes);
        unsigned short* Wt1b = (unsigned short*)(ws + off); off = align16(off + wbytes);
        int* rowptr = (int*)(ws + off); off = align16(off + (size_t)(M + 1) * 4);
        int* cnt    = (int*)(ws + off); off = align16(off + (size_t)M * 4);
        int* bsum   = (int*)(ws + off); off = align16(off + (size_t)256 * 4);
        int* hist   = (int*)(ws + off); off = align16(off + (size_t)256 * 256 * 4);
        unsigned* ep = (unsigned*)(ws + off); off = align16(off + (size_t)E * 4);
        unsigned short* yall = (unsigned short*)(ws + off);
        unsigned long long* e64a = (unsigned long long*)yall;   // transient
        unsigned long long* e64b = e64a + E;                    // transient

        // --- fused cooperative prep + CSR build (1 dispatch, was 9) ---
        int n4 = (int)(plane / 4);
        int Ei = E, Mi = M;
        void* cargs[] = {
            (void*)&x, (void*)&xb, (void*)&n4,
            (void*)&W0, (void*)&Wt0b, (void*)&W1, (void*)&Wt1b,
            (void*)&src, (void*)&dst, (void*)&etyp, (void*)&Ei,
            (void*)&hist, (void*)&bsum, (void*)&e64a, (void*)&e64b,
            (void*)&ep, (void*)&cnt, (void*)&rowptr, (void*)&Mi };
        hipLaunchCooperativeKernel((const void*)fused_prep_csr,
                                   dim3(256), dim3(256), cargs, 0, stream);

        const int Rtiles = (M + 127) / 128;
        const int octets = (Rtiles + 7) / 8;
        const int ggrid = octets * 16 * 8;
        const int npair = (M + 1) / 2;
        const int agrid = (npair * 64 + 255) / 256;   // 1 dst per half-wave

        // layer 1 (gemm overwrites the e64 region -- sort complete by now)
        gemm_mfma_bias_relu<<<ggrid, 256, 0, stream>>>(xb, Wt0b, b0, yall, M, Rtiles);
        aggregate2x<unsigned short><<<agrid, 256, 0, stream>>>(yall, ep, rowptr, h1b, M);
        // layer 2
        gemm_mfma_bias_relu<<<ggrid, 256, 0, stream>>>(h1b, Wt1b, b1, yall, M, Rtiles);
        aggregate2x<float><<<agrid, 256, 0, stream>>>(yall, ep, rowptr, out, M);
    } else {
        // fallback: fp32 per-relation GEMM + atomic scatter
        float* h1 = (float*)d_ws;
        float* y  = (float*)d_ws + plane;
        const dim3 gblk(256), ggrid2((M + 127) / 128, DIM / 128);
        hipMemsetAsync(h1, 0, plane * 4, stream);
        for (int r = 0; r < N_REL; r++) {
            gemm_bias_relu_f32<<<ggrid2, gblk, 0, stream>>>(
                x, W0 + (size_t)r * DIM * DIM, b0, y, M);
            scatter_rel<<<1024, 256, 0, stream>>>(y, src, dst, etyp, r, h1, E);
        }
        hipMemsetAsync(out, 0, plane * 4, stream);
        for (int r = 0; r < N_REL; r++) {
            gemm_bias_relu_f32<<<ggrid2, gblk, 0, stream>>>(
                h1, W1 + (size_t)r * DIM * DIM, b1, y, M);
            scatter_rel<<<1024, 256, 0, stream>>>(y, src, dst, etyp, r, out, E);
        }
    }
}

// Round 12
// 501.313 us; speedup vs baseline: 1.3360x; 1.3360x over previous
//
#include <hip/hip_runtime.h>

#define DIM 256
#define N_REL 8
#define NBLK 256     // blocks in build/scatter passes
#define NBH 256      // high-byte bins (dst < 65536)

typedef __attribute__((ext_vector_type(8))) short short8_t;
typedef __attribute__((ext_vector_type(4))) float float4_t;

// ---------------- bf16 helpers (manual, RNE) ----------------
__device__ inline unsigned short f2bf(float f) {
    unsigned u = __float_as_uint(f);
    u += 0x7FFFu + ((u >> 16) & 1u);
    return (unsigned short)(u >> 16);
}
__device__ inline float bf2f(unsigned short h) {
    return __uint_as_float(((unsigned)h) << 16);
}

// ---------------------------------------------------------------------------
// prep megakernel: {cast x->bf16 | transpose W0 | transpose W1}.
// R15 lesson: do NOT fuse these into a 1-block/CU cooperative kernel --
// memory-bound phases need wide grids for TLP (fused ran at 2.6% HBM).
// ---------------------------------------------------------------------------
__global__ __launch_bounds__(256) void prep_mega(
    const float* __restrict__ x, unsigned short* __restrict__ xb, int n4,
    const float* __restrict__ W0, unsigned short* __restrict__ Wt0,
    const float* __restrict__ W1, unsigned short* __restrict__ Wt1,
    int nCast, int nW)
{
    __shared__ float tile[32][33];
    const int b = blockIdx.x;
    const int t = threadIdx.x;
    if (b < nCast) {
        const int i = b * 256 + t;
        if (i < n4) {
            const float4 v = ((const float4*)x)[i];
            ushort4 o;
            o.x = f2bf(v.x); o.y = f2bf(v.y); o.z = f2bf(v.z); o.w = f2bf(v.w);
            ((ushort4*)xb)[i] = o;
        }
    } else {
        const int wi = b - nCast;
        const float* W = (wi < nW) ? W0 : W1;
        unsigned short* Wt = (wi < nW) ? Wt0 : Wt1;
        const int bb = (wi < nW) ? wi : wi - nW;
        const int rel = bb >> 6;
        const int bx = bb & 7, by = (bb >> 3) & 7;
        const int i0 = bx * 32, o0 = by * 32;
        const int tx = t & 31, ty = t >> 5;          // (32, 8)
        const float* Wr = W + (size_t)rel * DIM * DIM;
        unsigned short* Wtr = Wt + (size_t)rel * DIM * DIM;
#pragma unroll
        for (int j = 0; j < 4; j++)
            tile[ty + 8 * j][tx] = Wr[(size_t)(i0 + ty + 8 * j) * DIM + o0 + tx];
        __syncthreads();
#pragma unroll
        for (int j = 0; j < 4; j++)
            Wtr[(size_t)(o0 + ty + 8 * j) * DIM + i0 + tx] =
                f2bf(tile[tx][ty + 8 * j]);
    }
}

// ---------------------------------------------------------------------------
// Atomic-free CSR build: MSD bucket sort by dst, zero global atomics [R13].
// key u64 = [dst:16 @bit32][et:16 @bit16][src:16 @bit0]; payload (low u32)
// is exactly the ep format (et<<16|src).
// e64a/e64b transients alias the yall region (dead before first GEMM).
// ---------------------------------------------------------------------------
__global__ __launch_bounds__(256) void build_keys_hist(
    const int* __restrict__ src, const int* __restrict__ dst,
    const int* __restrict__ et, int E,
    unsigned long long* __restrict__ e0, int* __restrict__ hist)
{
    __shared__ int lh[NBH];
    const int t = threadIdx.x, b = blockIdx.x;
    lh[t] = 0;
    __syncthreads();
    const int chunk = (E + NBLK - 1) / NBLK;
    const int lo = b * chunk, hi = min(lo + chunk, E);
    for (int i = lo + t; i < hi; i += 256) {
        const unsigned d = (unsigned)dst[i];
        e0[i] = ((unsigned long long)d << 32) |
                ((unsigned)((et[i] << 16) | src[i]));
        atomicAdd(&lh[d >> 8], 1);          // LDS atomic (fast, banked)
    }
    __syncthreads();
    hist[t * NBLK + b] = lh[t];
}

// Generic exclusive-scan pair (n <= 65536 -> nb <= 64). outArr may alias a
// (each block reads only its own range before writing it).
__global__ __launch_bounds__(256) void scan_g_blocksums(
    const int* __restrict__ a, int n, int* __restrict__ bsum)
{
    __shared__ int red[256];
    const int t = threadIdx.x;
    const int base = blockIdx.x * 1024 + t * 4;
    int s = 0;
#pragma unroll
    for (int j = 0; j < 4; j++) {
        const int i = base + j;
        if (i < n) s += a[i];
    }
    red[t] = s;
    __syncthreads();
#pragma unroll
    for (int off = 128; off > 0; off >>= 1) {
        if (t < off) red[t] += red[t + off];
        __syncthreads();
    }
    if (t == 0) bsum[blockIdx.x] = red[0];
}

__global__ __launch_bounds__(256) void scan_g_write(
    const int* __restrict__ a, int n, const int* __restrict__ bsum, int nb,
    int* __restrict__ outArr, int* __restrict__ totalSlot)
{
    __shared__ int sb[64];
    __shared__ int sh[256];
    const int t = threadIdx.x;
    if (t < 64) sb[t] = (t < nb) ? bsum[t] : 0;
    __syncthreads();
    for (int off = 1; off < 64; off <<= 1) {
        int v = 0;
        if (t < 64) v = sb[t] + ((t >= off) ? sb[t - off] : 0);
        __syncthreads();
        if (t < 64) sb[t] = v;
        __syncthreads();
    }
    const int run0 = (blockIdx.x == 0) ? 0 : sb[blockIdx.x - 1];
    const int total = sb[nb - 1];

    const int base = blockIdx.x * 1024 + t * 4;
    int v[4];
#pragma unroll
    for (int j = 0; j < 4; j++) {
        const int i = base + j;
        v[j] = (i < n) ? a[i] : 0;
    }
    sh[t] = v[0] + v[1] + v[2] + v[3];
    __syncthreads();
    for (int off = 1; off < 256; off <<= 1) {
        const int add = (t >= off) ? sh[t - off] : 0;
        __syncthreads();
        sh[t] += add;
        __syncthreads();
    }
    int run = run0 + ((t == 0) ? 0 : sh[t - 1]);
#pragma unroll
    for (int j = 0; j < 4; j++) {
        const int i = base + j;
        if (i < n) outArr[i] = run;
        run += v[j];
    }
    if (totalSlot && (int)blockIdx.x == nb - 1 && t == 255) *totalSlot = total;
}

// Pass B: scatter into high-byte buckets. Base = scanned hist (stable across
// blocks); local rank via LDS atomic (order within (bin,blk) is run-varying,
// which is safe: aggregate sums in fp64, order-independent -- R11-verified).
__global__ __launch_bounds__(256) void scatter_pass1(
    const unsigned long long* __restrict__ e0, int E,
    const int* __restrict__ histx, unsigned long long* __restrict__ e1)
{
    __shared__ int lbase[NBH];
    __shared__ int lrun[NBH];
    const int t = threadIdx.x, b = blockIdx.x;
    lbase[t] = histx[t * NBLK + b];
    lrun[t] = 0;
    __syncthreads();
    const int chunk = (E + NBLK - 1) / NBLK;
    const int lo = b * chunk, hi = min(lo + chunk, E);
    for (int i = lo + t; i < hi; i += 256) {
        const unsigned long long v = e0[i];
        const int bin = (int)(v >> 40) & 0xFF;
        const int pos = lbase[bin] + atomicAdd(&lrun[bin], 1);
        e1[pos] = v;
    }
}

// Pass C: one block per high-byte bucket; LDS counting sort on dst low byte.
// Writes final ep + per-dst cnt (single writer per dst, deterministic).
__global__ __launch_bounds__(256) void bucket_sort(
    const unsigned long long* __restrict__ e1, int E,
    const int* __restrict__ histx,
    unsigned* __restrict__ ep, int* __restrict__ cnt)
{
    __shared__ int lh[256], lincl[256], lexcl[256], lrun[256];
    const int t = threadIdx.x;
    const int h = blockIdx.x;
    const int start = histx[h * NBLK];
    const int end = (h == NBH - 1) ? E : histx[(h + 1) * NBLK];
    if (end <= start) return;            // uniform across block
    lh[t] = 0;
    __syncthreads();
    for (int i = start + t; i < end; i += 256)
        atomicAdd(&lh[(int)(e1[i] >> 32) & 0xFF], 1);
    __syncthreads();
    const int v = lh[t];
    lincl[t] = v;
    __syncthreads();
    for (int off = 1; off < 256; off <<= 1) {
        const int add = (t >= off) ? lincl[t - off] : 0;
        __syncthreads();
        lincl[t] += add;
        __syncthreads();
    }
    lexcl[t] = lincl[t] - v;
    lrun[t] = 0;
    if (v > 0) cnt[(h << 8) | t] = v;    // dst = h*256 + t
    __syncthreads();
    for (int i = start + t; i < end; i += 256) {
        const unsigned long long x = e1[i];
        const int low = (int)(x >> 32) & 0xFF;
        const int pos = lexcl[low] + atomicAdd(&lrun[low], 1);
        ep[start + pos] = (unsigned)(x & 0xFFFFFFFFu);
    }
}

// ---------------------------------------------------------------------------
// Yall[rel][M][256] = relu(Xb @ W[rel] + bias) in bf16.  [R13-verified]
// Tile 128x128, BK=32, 4 waves of 64x64 (4x4 mfma_f32_16x16x32_bf16).
// global_load_lds width=16, XOR seg swizzle on BOTH sides (rule 21),
// 2-buffer vmcnt(4) schedule, R9 2-round epilogue.
// R16: Y stores are NON-TEMPORAL -- yall (205MB) has zero pre-eviction reuse
// (L2=32MB; R14 proved MALL is read-allocate, aggregate re-reads from HBM
// regardless), so write-allocate only churns L2 lines A/B fetches need.
// R14 lesson: yall locality schemes can't help the aggregate; ~83us/layer is
// its dataflow floor.
// ---------------------------------------------------------------------------
__global__ __launch_bounds__(256) void gemm_mfma_bias_relu(
    const unsigned short* __restrict__ Xb,    // [M][256]
    const unsigned short* __restrict__ Wtb,   // [R][256out][256in]
    const float* __restrict__ bias,           // [256]
    unsigned short* __restrict__ Yall, int M, int Rtiles)
{
    __shared__ __align__(16) short smem[16384];   // 32 KiB, 2 buffers

    const unsigned L = blockIdx.x;
    const int xcd = L & 7;
    const unsigned g = L >> 3;
    const int combo = g & 15;                 // (ntile, rel)
    const int rt = (int)((g >> 4) << 3) | xcd;
    if (rt >= Rtiles) return;
    const int m0 = rt * 128;
    const int n0 = (combo & 1) * 128;
    const int rel = combo >> 1;

    const unsigned short* Wt = Wtb + (size_t)rel * DIM * DIM;
    unsigned short* Y = Yall + (size_t)rel * M * DIM;

    const int t = threadIdx.x;
    const int lane = t & 63;
    const int w = t >> 6;
    const int wr = w & 1, wc = w >> 1;
    const int r = lane & 15, q = lane >> 4;

    const int sl = lane & 3;
    const int rsub = lane >> 2;
    const unsigned short* gA[2];
    const unsigned short* gB[2];
#pragma unroll
    for (int h = 0; h < 2; h++) {
        const int row = h * 64 + w * 16 + rsub;
        const int gseg = sl ^ ((row >> 1) & 3);          // pre-swizzled source
        gA[h] = Xb + (size_t)(m0 + row) * DIM + gseg * 8;
        gB[h] = Wt + (size_t)(n0 + row) * DIM + gseg * 8;
    }

    const int swz = (q ^ ((r >> 1) & 3)) * 8;
    int offA[4], offB[4];
#pragma unroll
    for (int mi = 0; mi < 4; mi++)
        offA[mi] = (wr * 64 + mi * 16 + r) * 32 + swz;
#pragma unroll
    for (int ni = 0; ni < 4; ni++)
        offB[ni] = (wc * 64 + ni * 16 + r) * 32 + swz;

    float4_t acc[4][4];
#pragma unroll
    for (int i = 0; i < 4; i++)
#pragma unroll
        for (int j = 0; j < 4; j++) {
            float4_t z = {0.f, 0.f, 0.f, 0.f};
            acc[i][j] = z;
        }

#define STAGE(ks, bsel)                                                         \
    {                                                                           \
        const int k0_ = (ks) * 32;                                              \
        short* Ad_ = smem + ((bsel) ? 8192 : 0);                                \
        short* Bd_ = Ad_ + 4096;                                                \
        _Pragma("unroll")                                                       \
        for (int h = 0; h < 2; h++) {                                           \
            __builtin_amdgcn_global_load_lds(                                   \
                (const __attribute__((address_space(1))) unsigned int*)(gA[h] + k0_), \
                (__attribute__((address_space(3))) unsigned int*)(Ad_ + h * 2048 + w * 512), \
                16, 0, 0);                                                      \
            __builtin_amdgcn_global_load_lds(                                   \
                (const __attribute__((address_space(1))) unsigned int*)(gB[h] + k0_), \
                (__attribute__((address_space(3))) unsigned int*)(Bd_ + h * 2048 + w * 512), \
                16, 0, 0);                                                      \
        }                                                                       \
    }

    STAGE(0, 0);
#pragma unroll 1
    for (int ks = 0; ks < 8; ks++) {
        const int cur = ks & 1;
        if (ks < 7) {
            STAGE(ks + 1, cur ^ 1);
            asm volatile("s_waitcnt vmcnt(4)" ::: "memory");
        } else {
            asm volatile("s_waitcnt vmcnt(0)" ::: "memory");
        }
        asm volatile("s_barrier" ::: "memory");

        const short* As_b = smem + (cur ? 8192 : 0);
        const short* Bs_b = As_b + 4096;
        short8_t af[4], bf[4];
#pragma unroll
        for (int mi = 0; mi < 4; mi++)
            af[mi] = *(const short8_t*)&As_b[offA[mi]];
#pragma unroll
        for (int ni = 0; ni < 4; ni++)
            bf[ni] = *(const short8_t*)&Bs_b[offB[ni]];
#pragma unroll
        for (int mi = 0; mi < 4; mi++)
#pragma unroll
            for (int ni = 0; ni < 4; ni++)
                acc[mi][ni] = __builtin_amdgcn_mfma_f32_16x16x32_bf16(
                    af[mi], bf[ni], acc[mi][ni], 0, 0, 0);
        asm volatile("s_barrier" ::: "memory");
    }
#undef STAGE

    // ---- epilogue: bias+relu, LDS-staged coalesced bf16 NT stores ----
    short* St = smem;

    float bv[4];
#pragma unroll
    for (int ni = 0; ni < 4; ni++)
        bv[ni] = bias[n0 + wc * 64 + ni * 16 + r];

#pragma unroll
    for (int mp = 0; mp < 2; mp++) {
#pragma unroll
        for (int s = 0; s < 2; s++) {
#pragma unroll
            for (int ni = 0; ni < 4; ni++) {
#pragma unroll
                for (int e = 0; e < 4; e++) {
                    const int rl = s * 32 + wr * 16 + q * 4 + e;
                    const int col = wc * 64 + ni * 16 + r;
                    St[rl * 136 + col] =
                        f2bf(fmaxf(acc[mp * 2 + s][ni][e] + bv[ni], 0.f));
                }
            }
        }
        __syncthreads();
#pragma unroll
        for (int j = 0; j < 4; j++) {
            const int id = t + 256 * j;
            const int rl2 = id >> 4;
            const int ch = id & 15;
            const int s = rl2 >> 5;
            const int rl = rl2 & 31;
            const int grow = m0 + (rl >> 4) * 64 + (mp * 2 + s) * 16 + (rl & 15);
            const short8_t v = *(const short8_t*)&St[rl2 * 136 + ch * 8];
            if (grow < M)
                __builtin_nontemporal_store(
                    v, (short8_t*)&Y[(size_t)grow * DIM + n0 + ch * 8]);
        }
        if (mp == 0) __syncthreads();
    }
}

// -------- aggregate: one dst per HALF-WAVE, fp64 accumulators [R13] --------
// fp64 sums are order-independent (~2^-53 rel) -> replay-deterministic under
// run-varying ep order. FETCH 247MB = unique yall re-read from HBM at ~47%
// random-512B efficiency -- the dataflow floor (R9/R10/R14 all null).
// R16: output stores non-temporal (h1b/out have no pre-eviction reuse).
// NOTE: nontemporal builtin needs ext_vector types (float4_t), NOT HIP's
// float4 class (R16 compile error).
template <typename OT>
__global__ __launch_bounds__(256) void aggregate2x(
    const unsigned short* __restrict__ yall,   // [R][M][256]
    const unsigned* __restrict__ ep, const int* __restrict__ rowptr,
    OT* __restrict__ out, int M)
{
    const int lane = threadIdx.x & 63;
    const int half = lane >> 5;     // which dst of the pair
    const int cl = lane & 31;       // 16B chunk within message row
    const int wv = (blockIdx.x * blockDim.x + threadIdx.x) >> 6;
    const int nw = (gridDim.x * blockDim.x) >> 6;
    const size_t plane = (size_t)M * DIM;
    const int npair = (M + 1) >> 1;

    for (int pr = wv; pr < npair; pr += nw) {
        const int d = 2 * pr + half;
        const bool live = (d < M);
        double acc[8];
#pragma unroll
        for (int j = 0; j < 8; j++) acc[j] = 0.0;

        int beg = 0, end = 0;
        if (live) { beg = rowptr[d]; end = rowptr[d + 1]; }

        for (int c0 = beg; c0 < end; c0 += 32) {
            const int n = min(32, end - c0);
            const unsigned myep = (c0 + cl < end) ? ep[c0 + cl] : 0u;
            for (int i = 0; i < n; i += 4) {
                short8_t u[4];
#pragma unroll
                for (int j = 0; j < 4; j++) {
                    const unsigned p = __shfl(myep, half * 32 + ((i + j) & 31));
                    u[j] = *(const short8_t*)(
                        yall + (size_t)(p >> 16) * plane +
                        (size_t)(p & 0xFFFFu) * DIM + cl * 8);
                }
#pragma unroll
                for (int j = 0; j < 4; j++) {
                    if (i + j < n) {
#pragma unroll
                        for (int k = 0; k < 8; k++)
                            acc[k] += (double)bf2f((unsigned short)u[j][k]);
                    }
                }
            }
        }
        if (live) {
            OT* dp = out + (size_t)d * DIM + cl * 8;
            if (sizeof(OT) == 4) {
                float4_t o0, o1;
                o0[0] = (float)acc[0]; o0[1] = (float)acc[1];
                o0[2] = (float)acc[2]; o0[3] = (float)acc[3];
                o1[0] = (float)acc[4]; o1[1] = (float)acc[5];
                o1[2] = (float)acc[6]; o1[3] = (float)acc[7];
                __builtin_nontemporal_store(o0, (float4_t*)((float*)dp));
                __builtin_nontemporal_store(o1, (float4_t*)((float*)dp) + 1);
            } else {
                short8_t v;
#pragma unroll
                for (int j = 0; j < 8; j++) v[j] = (short)f2bf((float)acc[j]);
                __builtin_nontemporal_store(v, (short8_t*)((unsigned short*)dp));
            }
        }
    }
}

// ---------------- fallback: fp32 vector GEMM + atomic scatter ----------------
__global__ __launch_bounds__(256) void gemm_bias_relu_f32(
    const float* __restrict__ A, const float* __restrict__ B,
    const float* __restrict__ bias, float* __restrict__ Y, int M)
{
    __shared__ float Asf[16][132];
    __shared__ float Bsf[16][128];
    const int t = threadIdx.x;
    const int tx = t & 15, ty = t >> 4;
    const int row0 = blockIdx.x * 128, col0 = blockIdx.y * 128;
    float acc[8][8];
#pragma unroll
    for (int i = 0; i < 8; i++)
#pragma unroll
        for (int j = 0; j < 8; j++) acc[i][j] = 0.f;
    const int arow = t >> 2, akseg = (t & 3) * 4;
    const int bk0 = t >> 5, bcol = (t & 31) * 4;
    for (int k0 = 0; k0 < DIM; k0 += 16) {
#pragma unroll
        for (int h = 0; h < 2; h++) {
            const int row = row0 + arow + h * 64;
            float4 av = (row < M) ? *(const float4*)(A + (size_t)row * DIM + k0 + akseg)
                                  : make_float4(0, 0, 0, 0);
            Asf[akseg + 0][arow + h * 64] = av.x;
            Asf[akseg + 1][arow + h * 64] = av.y;
            Asf[akseg + 2][arow + h * 64] = av.z;
            Asf[akseg + 3][arow + h * 64] = av.w;
        }
#pragma unroll
        for (int h = 0; h < 2; h++) {
            const int krow = bk0 + h * 8;
            *(float4*)&Bsf[krow][bcol] =
                *(const float4*)(B + (size_t)(k0 + krow) * DIM + col0 + bcol);
        }
        __syncthreads();
#pragma unroll
        for (int k = 0; k < 16; k++) {
            float a[8], bvv[8];
            *(float4*)&a[0] = *(const float4*)&Asf[k][ty * 4];
            *(float4*)&a[4] = *(const float4*)&Asf[k][64 + ty * 4];
            *(float4*)&bvv[0] = *(const float4*)&Bsf[k][tx * 4];
            *(float4*)&bvv[4] = *(const float4*)&Bsf[k][64 + tx * 4];
#pragma unroll
            for (int i = 0; i < 8; i++)
#pragma unroll
                for (int j = 0; j < 8; j++) acc[i][j] = fmaf(a[i], bvv[j], acc[i][j]);
        }
        __syncthreads();
    }
#pragma unroll
    for (int im = 0; im < 2; im++)
#pragma unroll
        for (int i = 0; i < 4; i++) {
            const int row = row0 + im * 64 + ty * 4 + i;
            if (row >= M) continue;
#pragma unroll
            for (int jm = 0; jm < 2; jm++) {
                const int col = col0 + jm * 64 + tx * 4;
                const float4 bb = *(const float4*)(bias + col);
                float4 o;
                o.x = fmaxf(acc[im * 4 + i][jm * 4 + 0] + bb.x, 0.f);
                o.y = fmaxf(acc[im * 4 + i][jm * 4 + 1] + bb.y, 0.f);
                o.z = fmaxf(acc[im * 4 + i][jm * 4 + 2] + bb.z, 0.f);
                o.w = fmaxf(acc[im * 4 + i][jm * 4 + 3] + bb.w, 0.f);
                *(float4*)(Y + (size_t)row * DIM + col) = o;
            }
        }
}

__global__ __launch_bounds__(256) void scatter_rel(
    const float* __restrict__ y, const int* __restrict__ src,
    const int* __restrict__ dst, const int* __restrict__ et,
    int rel, float* __restrict__ out, int n_edges)
{
    const int lane = threadIdx.x & 63;
    const int wave = (blockIdx.x * blockDim.x + threadIdx.x) >> 6;
    const int nwaves = (gridDim.x * blockDim.x) >> 6;
    for (int e = wave; e < n_edges; e += nwaves) {
        if (et[e] != rel) continue;
        const float4 v = *(const float4*)(y + (size_t)src[e] * DIM + lane * 4);
        float* o = out + (size_t)dst[e] * DIM + lane * 4;
        atomicAdd(o + 0, v.x);
        atomicAdd(o + 1, v.y);
        atomicAdd(o + 2, v.z);
        atomicAdd(o + 3, v.w);
    }
}

static inline size_t align16(size_t x) { return (x + 15) & ~(size_t)15; }

extern "C" void kernel_launch(void* const* d_in, const int* in_sizes, int n_in,
                              void* d_out, int out_size, void* d_ws, size_t ws_size,
                              hipStream_t stream)
{
    const float* x  = (const float*)d_in[0];
    const float* W0 = (const float*)d_in[1];
    const float* b0 = (const float*)d_in[2];
    const float* W1 = (const float*)d_in[3];
    const float* b1 = (const float*)d_in[4];
    const int* eidx = (const int*)d_in[5];
    const int* etyp = (const int*)d_in[6];

    const int M = in_sizes[0] / DIM;   // 50000
    const int E = in_sizes[6];         // 800000
    const int* src = eidx;
    const int* dst = eidx + E;
    float* out = (float*)d_out;

    const size_t plane = (size_t)M * DIM;
    const size_t wbytes = (size_t)N_REL * DIM * DIM * 2;
    const size_t yall_bytes = (size_t)N_REL * plane * 2;   // 204.8MB

    // e64a/e64b (2*E*8 = 12.8MB) live INSIDE the yall region (R13) -- dead
    // before the first GEMM writes yall. `need` = R11-proven footprint.
    const size_t need = align16(plane * 2)              // h1b
                      + align16(plane * 2)              // xb
                      + 2 * align16(wbytes)             // Wt0b, Wt1b
                      + align16((size_t)(M + 1) * 4)    // rowptr
                      + align16((size_t)M * 4)          // cnt
                      + align16((size_t)256 * 4)        // bsum
                      + align16((size_t)NBH * NBLK * 4) // hist
                      + align16((size_t)E * 4)          // ep
                      + align16(yall_bytes);            // yall (e64a/b alias)

    if (M < 65536 && ws_size >= need && yall_bytes >= 2 * (size_t)E * 8) {
        char* ws = (char*)d_ws;
        size_t off = 0;
        unsigned short* h1b  = (unsigned short*)(ws + off); off = align16(off + plane * 2);
        unsigned short* xb   = (unsigned short*)(ws + off); off = align16(off + plane * 2);
        unsigned short* Wt0b = (unsigned short*)(ws + off); off = align16(off + wbytes);
        unsigned short* Wt1b = (unsigned short*)(ws + off); off = align16(off + wbytes);
        int* rowptr = (int*)(ws + off); off = align16(off + (size_t)(M + 1) * 4);
        int* cnt    = (int*)(ws + off); off = align16(off + (size_t)M * 4);
        int* bsum   = (int*)(ws + off); off = align16(off + (size_t)256 * 4);
        int* hist   = (int*)(ws + off); off = align16(off + (size_t)NBH * NBLK * 4);
        unsigned* ep = (unsigned*)(ws + off); off = align16(off + (size_t)E * 4);
        unsigned short* yall = (unsigned short*)(ws + off);
        unsigned long long* e64a = (unsigned long long*)yall;   // transient
        unsigned long long* e64b = e64a + E;                    // transient

        // --- prep megakernel: cast + 2 transposes
        const int n4 = (int)(plane / 4);
        const int nCast = (n4 + 255) / 256;
        const int nW = 512;                 // 8x8 tiles x 8 rels
        prep_mega<<<nCast + 2 * nW, 256, 0, stream>>>(
            x, xb, n4, W0, Wt0b, W1, Wt1b, nCast, nW);

        // --- atomic-free CSR build: MSD bucket sort by dst (R13-verified)
        hipMemsetAsync(cnt, 0, (size_t)M * 4, stream);
        build_keys_hist<<<NBLK, 256, 0, stream>>>(src, dst, etyp, E, e64a, hist);
        const int nhist = NBH * NBLK;                      // 65536
        const int nbh = (nhist + 1023) / 1024;             // 64
        scan_g_blocksums<<<nbh, 256, 0, stream>>>(hist, nhist, bsum);
        scan_g_write<<<nbh, 256, 0, stream>>>(hist, nhist, bsum, nbh, hist, (int*)nullptr);
        scatter_pass1<<<NBLK, 256, 0, stream>>>(e64a, E, hist, e64b);
        bucket_sort<<<NBH, 256, 0, stream>>>(e64b, E, hist, ep, cnt);
        const int nb = (M + 1023) / 1024;                  // 49
        scan_g_blocksums<<<nb, 256, 0, stream>>>(cnt, M, bsum);
        scan_g_write<<<nb, 256, 0, stream>>>(cnt, M, bsum, nb, rowptr, &rowptr[M]);

        const int Rtiles = (M + 127) / 128;
        const int octets = (Rtiles + 7) / 8;
        const int ggrid = octets * 16 * 8;
        const int npair = (M + 1) / 2;
        const int agrid = (npair * 64 + 255) / 256;   // 1 dst per half-wave

        // layer 1 (gemm overwrites the e64 region -- sort complete by now)
        gemm_mfma_bias_relu<<<ggrid, 256, 0, stream>>>(xb, Wt0b, b0, yall, M, Rtiles);
        aggregate2x<unsigned short><<<agrid, 256, 0, stream>>>(yall, ep, rowptr, h1b, M);
        // layer 2
        gemm_mfma_bias_relu<<<ggrid, 256, 0, stream>>>(h1b, Wt1b, b1, yall, M, Rtiles);
        aggregate2x<float><<<agrid, 256, 0, stream>>>(yall, ep, rowptr, out, M);
    } else {
        // fallback: fp32 per-relation GEMM + atomic scatter
        float* h1 = (float*)d_ws;
        float* y  = (float*)d_ws + plane;
        const dim3 gblk(256), ggrid2((M + 127) / 128, DIM / 128);
        hipMemsetAsync(h1, 0, plane * 4, stream);
        for (int r = 0; r < N_REL; r++) {
            gemm_bias_relu_f32<<<ggrid2, gblk, 0, stream>>>(
                x, W0 + (size_t)r * DIM * DIM, b0, y, M);
            scatter_rel<<<1024, 256, 0, stream>>>(y, src, dst, etyp, r, h1, E);
        }
        hipMemsetAsync(out, 0, plane * 4, stream);
        for (int r = 0; r < N_REL; r++) {
            gemm_bias_relu_f32<<<ggrid2, gblk, 0, stream>>>(
                h1, W1 + (size_t)r * DIM * DIM, b1, y, M);
            scatter_rel<<<1024, 256, 0, stream>>>(y, src, dst, etyp, r, out, E);
        }
    }
}

// Round 13
// 463.472 us; speedup vs baseline: 1.4451x; 1.0816x over previous
//
#include <hip/hip_runtime.h>

#define DIM 256
#define N_REL 8
#define NBLK 1024    // blocks in build/scatter passes (R17: 4x wider)
#define NBH 256      // high-byte bins (dst < 65536)

typedef __attribute__((ext_vector_type(8))) short short8_t;
typedef __attribute__((ext_vector_type(4))) float float4_t;

// ---------------- bf16 helpers (manual, RNE) ----------------
__device__ inline unsigned short f2bf(float f) {
    unsigned u = __float_as_uint(f);
    u += 0x7FFFu + ((u >> 16) & 1u);
    return (unsigned short)(u >> 16);
}
__device__ inline float bf2f(unsigned short h) {
    return __uint_as_float(((unsigned)h) << 16);
}

// ---------------------------------------------------------------------------
// prep megakernel: {cast x->bf16 | transpose W0 | transpose W1}.
// R15 lesson: memory-bound phases need wide grids for TLP.
// ---------------------------------------------------------------------------
__global__ __launch_bounds__(256) void prep_mega(
    const float* __restrict__ x, unsigned short* __restrict__ xb, int n4,
    const float* __restrict__ W0, unsigned short* __restrict__ Wt0,
    const float* __restrict__ W1, unsigned short* __restrict__ Wt1,
    int nCast, int nW)
{
    __shared__ float tile[32][33];
    const int b = blockIdx.x;
    const int t = threadIdx.x;
    if (b < nCast) {
        const int i = b * 256 + t;
        if (i < n4) {
            const float4 v = ((const float4*)x)[i];
            ushort4 o;
            o.x = f2bf(v.x); o.y = f2bf(v.y); o.z = f2bf(v.z); o.w = f2bf(v.w);
            ((ushort4*)xb)[i] = o;
        }
    } else {
        const int wi = b - nCast;
        const float* W = (wi < nW) ? W0 : W1;
        unsigned short* Wt = (wi < nW) ? Wt0 : Wt1;
        const int bb = (wi < nW) ? wi : wi - nW;
        const int rel = bb >> 6;
        const int bx = bb & 7, by = (bb >> 3) & 7;
        const int i0 = bx * 32, o0 = by * 32;
        const int tx = t & 31, ty = t >> 5;          // (32, 8)
        const float* Wr = W + (size_t)rel * DIM * DIM;
        unsigned short* Wtr = Wt + (size_t)rel * DIM * DIM;
#pragma unroll
        for (int j = 0; j < 4; j++)
            tile[ty + 8 * j][tx] = Wr[(size_t)(i0 + ty + 8 * j) * DIM + o0 + tx];
        __syncthreads();
#pragma unroll
        for (int j = 0; j < 4; j++)
            Wtr[(size_t)(o0 + ty + 8 * j) * DIM + i0 + tx] =
                f2bf(tile[tx][ty + 8 * j]);
    }
}

// ---------------------------------------------------------------------------
// Atomic-free CSR build: MSD bucket sort by dst, zero global atomics [R13].
// key u64 = [dst:16 @bit32][et:16 @bit16][src:16 @bit0]; payload (low u32)
// is exactly the ep format (et<<16|src).
// R17: build/scatter at 1024 blocks (were 256 = 1 block/CU, latency-exposed);
// hist (1MB) aliases the yall transient region alongside e64a/e64b.
// ---------------------------------------------------------------------------
__global__ __launch_bounds__(256) void build_keys_hist(
    const int* __restrict__ src, const int* __restrict__ dst,
    const int* __restrict__ et, int E,
    unsigned long long* __restrict__ e0, int* __restrict__ hist)
{
    __shared__ int lh[NBH];
    const int t = threadIdx.x, b = blockIdx.x;
    lh[t] = 0;
    __syncthreads();
    const int chunk = (E + NBLK - 1) / NBLK;
    const int lo = b * chunk, hi = min(lo + chunk, E);
    for (int i = lo + t; i < hi; i += 256) {
        const unsigned d = (unsigned)dst[i];
        e0[i] = ((unsigned long long)d << 32) |
                ((unsigned)((et[i] << 16) | src[i]));
        atomicAdd(&lh[d >> 8], 1);          // LDS atomic (fast, banked)
    }
    __syncthreads();
    hist[t * NBLK + b] = lh[t];
}

// Generic exclusive-scan pair (n <= 262144 -> nb <= 256). outArr may alias a
// (each block reads only its own range before writing it).
__global__ __launch_bounds__(256) void scan_g_blocksums(
    const int* __restrict__ a, int n, int* __restrict__ bsum)
{
    __shared__ int red[256];
    const int t = threadIdx.x;
    const int base = blockIdx.x * 1024 + t * 4;
    int s = 0;
#pragma unroll
    for (int j = 0; j < 4; j++) {
        const int i = base + j;
        if (i < n) s += a[i];
    }
    red[t] = s;
    __syncthreads();
#pragma unroll
    for (int off = 128; off > 0; off >>= 1) {
        if (t < off) red[t] += red[t + off];
        __syncthreads();
    }
    if (t == 0) bsum[blockIdx.x] = red[0];
}

__global__ __launch_bounds__(256) void scan_g_write(
    const int* __restrict__ a, int n, const int* __restrict__ bsum, int nb,
    int* __restrict__ outArr, int* __restrict__ totalSlot)
{
    __shared__ int sb[256];
    __shared__ int sh[256];
    const int t = threadIdx.x;
    sb[t] = (t < nb) ? bsum[t] : 0;
    __syncthreads();
    for (int off = 1; off < 256; off <<= 1) {
        const int v = sb[t] + ((t >= off) ? sb[t - off] : 0);
        __syncthreads();
        sb[t] = v;
        __syncthreads();
    }
    const int run0 = (blockIdx.x == 0) ? 0 : sb[blockIdx.x - 1];
    const int total = sb[nb - 1];

    const int base = blockIdx.x * 1024 + t * 4;
    int v[4];
#pragma unroll
    for (int j = 0; j < 4; j++) {
        const int i = base + j;
        v[j] = (i < n) ? a[i] : 0;
    }
    sh[t] = v[0] + v[1] + v[2] + v[3];
    __syncthreads();
    for (int off = 1; off < 256; off <<= 1) {
        const int add = (t >= off) ? sh[t - off] : 0;
        __syncthreads();
        sh[t] += add;
        __syncthreads();
    }
    int run = run0 + ((t == 0) ? 0 : sh[t - 1]);
#pragma unroll
    for (int j = 0; j < 4; j++) {
        const int i = base + j;
        if (i < n) outArr[i] = run;
        run += v[j];
    }
    if (totalSlot && (int)blockIdx.x == nb - 1 && t == 255) *totalSlot = total;
}

// Pass B: scatter into high-byte buckets. Base = scanned hist (stable across
// blocks); local rank via LDS atomic (order within (bin,blk) is run-varying,
// which is safe: aggregate sums in fp64, order-independent -- R11-verified).
__global__ __launch_bounds__(256) void scatter_pass1(
    const unsigned long long* __restrict__ e0, int E,
    const int* __restrict__ histx, unsigned long long* __restrict__ e1)
{
    __shared__ int lbase[NBH];
    __shared__ int lrun[NBH];
    const int t = threadIdx.x, b = blockIdx.x;
    lbase[t] = histx[t * NBLK + b];
    lrun[t] = 0;
    __syncthreads();
    const int chunk = (E + NBLK - 1) / NBLK;
    const int lo = b * chunk, hi = min(lo + chunk, E);
    for (int i = lo + t; i < hi; i += 256) {
        const unsigned long long v = e0[i];
        const int bin = (int)(v >> 40) & 0xFF;
        const int pos = lbase[bin] + atomicAdd(&lrun[bin], 1);
        e1[pos] = v;
    }
}

// Pass C: one block per high-byte bucket; LDS counting sort on dst low byte.
// Writes final ep + per-dst cnt. R17: cnt written UNCONDITIONALLY (each dst
// has exactly one (bucket,thread) owner) -> the cnt memset dispatch is gone.
__global__ __launch_bounds__(256) void bucket_sort(
    const unsigned long long* __restrict__ e1, int E,
    const int* __restrict__ histx,
    unsigned* __restrict__ ep, int* __restrict__ cnt, int M)
{
    __shared__ int lh[256], lincl[256], lexcl[256], lrun[256];
    const int t = threadIdx.x;
    const int h = blockIdx.x;
    const int start = histx[h * NBLK];
    const int end = (h == NBH - 1) ? E : histx[(h + 1) * NBLK];
    lh[t] = 0;
    __syncthreads();
    for (int i = start + t; i < end; i += 256)
        atomicAdd(&lh[(int)(e1[i] >> 32) & 0xFF], 1);
    __syncthreads();
    const int v = lh[t];
    const int d = (h << 8) | t;
    if (d < M) cnt[d] = v;               // unconditional (zeros included)
    if (end <= start) return;            // uniform across block (after cnt)
    lincl[t] = v;
    __syncthreads();
    for (int off = 1; off < 256; off <<= 1) {
        const int add = (t >= off) ? lincl[t - off] : 0;
        __syncthreads();
        lincl[t] += add;
        __syncthreads();
    }
    lexcl[t] = lincl[t] - v;
    lrun[t] = 0;
    __syncthreads();
    for (int i = start + t; i < end; i += 256) {
        const unsigned long long x = e1[i];
        const int low = (int)(x >> 32) & 0xFF;
        const int pos = lexcl[low] + atomicAdd(&lrun[low], 1);
        ep[start + pos] = (unsigned)(x & 0xFFFFFFFFu);
    }
}

// ---------------------------------------------------------------------------
// Yall[rel][M][256] = relu(Xb @ W[rel] + bias) in bf16.  [R13-verified]
// Tile 128x128, BK=32, 4 waves of 64x64 (4x4 mfma_f32_16x16x32_bf16).
// global_load_lds width=16, XOR seg swizzle on BOTH sides (rule 21),
// 2-buffer vmcnt(4) schedule, R9 2-round epilogue. PLAIN stores:
// R16 showed NT stores bypass L2 write-combining -> partial-line HBM writes
// (WRITE_SIZE 200->241MB, dur 81->109us). Write-allocate HELPS here.
// R14 lesson: MALL is read-allocate; aggregate ~83us/layer is its floor.
// ---------------------------------------------------------------------------
__global__ __launch_bounds__(256) void gemm_mfma_bias_relu(
    const unsigned short* __restrict__ Xb,    // [M][256]
    const unsigned short* __restrict__ Wtb,   // [R][256out][256in]
    const float* __restrict__ bias,           // [256]
    unsigned short* __restrict__ Yall, int M, int Rtiles)
{
    __shared__ __align__(16) short smem[16384];   // 32 KiB, 2 buffers

    const unsigned L = blockIdx.x;
    const int xcd = L & 7;
    const unsigned g = L >> 3;
    const int combo = g & 15;                 // (ntile, rel)
    const int rt = (int)((g >> 4) << 3) | xcd;
    if (rt >= Rtiles) return;
    const int m0 = rt * 128;
    const int n0 = (combo & 1) * 128;
    const int rel = combo >> 1;

    const unsigned short* Wt = Wtb + (size_t)rel * DIM * DIM;
    unsigned short* Y = Yall + (size_t)rel * M * DIM;

    const int t = threadIdx.x;
    const int lane = t & 63;
    const int w = t >> 6;
    const int wr = w & 1, wc = w >> 1;
    const int r = lane & 15, q = lane >> 4;

    const int sl = lane & 3;
    const int rsub = lane >> 2;
    const unsigned short* gA[2];
    const unsigned short* gB[2];
#pragma unroll
    for (int h = 0; h < 2; h++) {
        const int row = h * 64 + w * 16 + rsub;
        const int gseg = sl ^ ((row >> 1) & 3);          // pre-swizzled source
        gA[h] = Xb + (size_t)(m0 + row) * DIM + gseg * 8;
        gB[h] = Wt + (size_t)(n0 + row) * DIM + gseg * 8;
    }

    const int swz = (q ^ ((r >> 1) & 3)) * 8;
    int offA[4], offB[4];
#pragma unroll
    for (int mi = 0; mi < 4; mi++)
        offA[mi] = (wr * 64 + mi * 16 + r) * 32 + swz;
#pragma unroll
    for (int ni = 0; ni < 4; ni++)
        offB[ni] = (wc * 64 + ni * 16 + r) * 32 + swz;

    float4_t acc[4][4];
#pragma unroll
    for (int i = 0; i < 4; i++)
#pragma unroll
        for (int j = 0; j < 4; j++) {
            float4_t z = {0.f, 0.f, 0.f, 0.f};
            acc[i][j] = z;
        }

#define STAGE(ks, bsel)                                                         \
    {                                                                           \
        const int k0_ = (ks) * 32;                                              \
        short* Ad_ = smem + ((bsel) ? 8192 : 0);                                \
        short* Bd_ = Ad_ + 4096;                                                \
        _Pragma("unroll")                                                       \
        for (int h = 0; h < 2; h++) {                                           \
            __builtin_amdgcn_global_load_lds(                                   \
                (const __attribute__((address_space(1))) unsigned int*)(gA[h] + k0_), \
                (__attribute__((address_space(3))) unsigned int*)(Ad_ + h * 2048 + w * 512), \
                16, 0, 0);                                                      \
            __builtin_amdgcn_global_load_lds(                                   \
                (const __attribute__((address_space(1))) unsigned int*)(gB[h] + k0_), \
                (__attribute__((address_space(3))) unsigned int*)(Bd_ + h * 2048 + w * 512), \
                16, 0, 0);                                                      \
        }                                                                       \
    }

    STAGE(0, 0);
#pragma unroll 1
    for (int ks = 0; ks < 8; ks++) {
        const int cur = ks & 1;
        if (ks < 7) {
            STAGE(ks + 1, cur ^ 1);
            asm volatile("s_waitcnt vmcnt(4)" ::: "memory");
        } else {
            asm volatile("s_waitcnt vmcnt(0)" ::: "memory");
        }
        asm volatile("s_barrier" ::: "memory");

        const short* As_b = smem + (cur ? 8192 : 0);
        const short* Bs_b = As_b + 4096;
        short8_t af[4], bf[4];
#pragma unroll
        for (int mi = 0; mi < 4; mi++)
            af[mi] = *(const short8_t*)&As_b[offA[mi]];
#pragma unroll
        for (int ni = 0; ni < 4; ni++)
            bf[ni] = *(const short8_t*)&Bs_b[offB[ni]];
#pragma unroll
        for (int mi = 0; mi < 4; mi++)
#pragma unroll
            for (int ni = 0; ni < 4; ni++)
                acc[mi][ni] = __builtin_amdgcn_mfma_f32_16x16x32_bf16(
                    af[mi], bf[ni], acc[mi][ni], 0, 0, 0);
        asm volatile("s_barrier" ::: "memory");
    }
#undef STAGE

    // ---- epilogue: bias+relu, LDS-staged coalesced bf16 stores (2 rounds) ----
    short* St = smem;

    float bv[4];
#pragma unroll
    for (int ni = 0; ni < 4; ni++)
        bv[ni] = bias[n0 + wc * 64 + ni * 16 + r];

#pragma unroll
    for (int mp = 0; mp < 2; mp++) {
#pragma unroll
        for (int s = 0; s < 2; s++) {
#pragma unroll
            for (int ni = 0; ni < 4; ni++) {
#pragma unroll
                for (int e = 0; e < 4; e++) {
                    const int rl = s * 32 + wr * 16 + q * 4 + e;
                    const int col = wc * 64 + ni * 16 + r;
                    St[rl * 136 + col] =
                        f2bf(fmaxf(acc[mp * 2 + s][ni][e] + bv[ni], 0.f));
                }
            }
        }
        __syncthreads();
#pragma unroll
        for (int j = 0; j < 4; j++) {
            const int id = t + 256 * j;
            const int rl2 = id >> 4;
            const int ch = id & 15;
            const int s = rl2 >> 5;
            const int rl = rl2 & 31;
            const int grow = m0 + (rl >> 4) * 64 + (mp * 2 + s) * 16 + (rl & 15);
            const short8_t v = *(const short8_t*)&St[rl2 * 136 + ch * 8];
            if (grow < M)
                *(short8_t*)&Y[(size_t)grow * DIM + n0 + ch * 8] = v;
        }
        if (mp == 0) __syncthreads();
    }
}

// -------- aggregate: one dst per HALF-WAVE, fp64 accumulators [R13] --------
// fp64 sums are order-independent (~2^-53 rel) -> replay-deterministic under
// run-varying ep order. FETCH 247MB = unique yall re-read from HBM at ~47%
// random-512B efficiency -- the dataflow floor (R9/R10/R14 all null).
template <typename OT>
__global__ __launch_bounds__(256) void aggregate2x(
    const unsigned short* __restrict__ yall,   // [R][M][256]
    const unsigned* __restrict__ ep, const int* __restrict__ rowptr,
    OT* __restrict__ out, int M)
{
    const int lane = threadIdx.x & 63;
    const int half = lane >> 5;     // which dst of the pair
    const int cl = lane & 31;       // 16B chunk within message row
    const int wv = (blockIdx.x * blockDim.x + threadIdx.x) >> 6;
    const int nw = (gridDim.x * blockDim.x) >> 6;
    const size_t plane = (size_t)M * DIM;
    const int npair = (M + 1) >> 1;

    for (int pr = wv; pr < npair; pr += nw) {
        const int d = 2 * pr + half;
        const bool live = (d < M);
        double acc[8];
#pragma unroll
        for (int j = 0; j < 8; j++) acc[j] = 0.0;

        int beg = 0, end = 0;
        if (live) { beg = rowptr[d]; end = rowptr[d + 1]; }

        for (int c0 = beg; c0 < end; c0 += 32) {
            const int n = min(32, end - c0);
            const unsigned myep = (c0 + cl < end) ? ep[c0 + cl] : 0u;
            for (int i = 0; i < n; i += 4) {
                short8_t u[4];
#pragma unroll
                for (int j = 0; j < 4; j++) {
                    const unsigned p = __shfl(myep, half * 32 + ((i + j) & 31));
                    u[j] = *(const short8_t*)(
                        yall + (size_t)(p >> 16) * plane +
                        (size_t)(p & 0xFFFFu) * DIM + cl * 8);
                }
#pragma unroll
                for (int j = 0; j < 4; j++) {
                    if (i + j < n) {
#pragma unroll
                        for (int k = 0; k < 8; k++)
                            acc[k] += (double)bf2f((unsigned short)u[j][k]);
                    }
                }
            }
        }
        if (live) {
            OT* dp = out + (size_t)d * DIM + cl * 8;
            if (sizeof(OT) == 4) {
                *(float4*)((float*)dp) = make_float4(
                    (float)acc[0], (float)acc[1], (float)acc[2], (float)acc[3]);
                *(float4*)((float*)dp + 4) = make_float4(
                    (float)acc[4], (float)acc[5], (float)acc[6], (float)acc[7]);
            } else {
                short8_t v;
#pragma unroll
                for (int j = 0; j < 8; j++) v[j] = (short)f2bf((float)acc[j]);
                *(short8_t*)((unsigned short*)dp) = v;
            }
        }
    }
}

// ---------------- fallback: fp32 vector GEMM + atomic scatter ----------------
__global__ __launch_bounds__(256) void gemm_bias_relu_f32(
    const float* __restrict__ A, const float* __restrict__ B,
    const float* __restrict__ bias, float* __restrict__ Y, int M)
{
    __shared__ float Asf[16][132];
    __shared__ float Bsf[16][128];
    const int t = threadIdx.x;
    const int tx = t & 15, ty = t >> 4;
    const int row0 = blockIdx.x * 128, col0 = blockIdx.y * 128;
    float acc[8][8];
#pragma unroll
    for (int i = 0; i < 8; i++)
#pragma unroll
        for (int j = 0; j < 8; j++) acc[i][j] = 0.f;
    const int arow = t >> 2, akseg = (t & 3) * 4;
    const int bk0 = t >> 5, bcol = (t & 31) * 4;
    for (int k0 = 0; k0 < DIM; k0 += 16) {
#pragma unroll
        for (int h = 0; h < 2; h++) {
            const int row = row0 + arow + h * 64;
            float4 av = (row < M) ? *(const float4*)(A + (size_t)row * DIM + k0 + akseg)
                                  : make_float4(0, 0, 0, 0);
            Asf[akseg + 0][arow + h * 64] = av.x;
            Asf[akseg + 1][arow + h * 64] = av.y;
            Asf[akseg + 2][arow + h * 64] = av.z;
            Asf[akseg + 3][arow + h * 64] = av.w;
        }
#pragma unroll
        for (int h = 0; h < 2; h++) {
            const int krow = bk0 + h * 8;
            *(float4*)&Bsf[krow][bcol] =
                *(const float4*)(B + (size_t)(k0 + krow) * DIM + col0 + bcol);
        }
        __syncthreads();
#pragma unroll
        for (int k = 0; k < 16; k++) {
            float a[8], bvv[8];
            *(float4*)&a[0] = *(const float4*)&Asf[k][ty * 4];
            *(float4*)&a[4] = *(const float4*)&Asf[k][64 + ty * 4];
            *(float4*)&bvv[0] = *(const float4*)&Bsf[k][tx * 4];
            *(float4*)&bvv[4] = *(const float4*)&Bsf[k][64 + tx * 4];
#pragma unroll
            for (int i = 0; i < 8; i++)
#pragma unroll
                for (int j = 0; j < 8; j++) acc[i][j] = fmaf(a[i], bvv[j], acc[i][j]);
        }
        __syncthreads();
    }
#pragma unroll
    for (int im = 0; im < 2; im++)
#pragma unroll
        for (int i = 0; i < 4; i++) {
            const int row = row0 + im * 64 + ty * 4 + i;
            if (row >= M) continue;
#pragma unroll
            for (int jm = 0; jm < 2; jm++) {
                const int col = col0 + jm * 64 + tx * 4;
                const float4 bb = *(const float4*)(bias + col);
                float4 o;
                o.x = fmaxf(acc[im * 4 + i][jm * 4 + 0] + bb.x, 0.f);
                o.y = fmaxf(acc[im * 4 + i][jm * 4 + 1] + bb.y, 0.f);
                o.z = fmaxf(acc[im * 4 + i][jm * 4 + 2] + bb.z, 0.f);
                o.w = fmaxf(acc[im * 4 + i][jm * 4 + 3] + bb.w, 0.f);
                *(float4*)(Y + (size_t)row * DIM + col) = o;
            }
        }
}

__global__ __launch_bounds__(256) void scatter_rel(
    const float* __restrict__ y, const int* __restrict__ src,
    const int* __restrict__ dst, const int* __restrict__ et,
    int rel, float* __restrict__ out, int n_edges)
{
    const int lane = threadIdx.x & 63;
    const int wave = (blockIdx.x * blockDim.x + threadIdx.x) >> 6;
    const int nwaves = (gridDim.x * blockDim.x) >> 6;
    for (int e = wave; e < n_edges; e += nwaves) {
        if (et[e] != rel) continue;
        const float4 v = *(const float4*)(y + (size_t)src[e] * DIM + lane * 4);
        float* o = out + (size_t)dst[e] * DIM + lane * 4;
        atomicAdd(o + 0, v.x);
        atomicAdd(o + 1, v.y);
        atomicAdd(o + 2, v.z);
        atomicAdd(o + 3, v.w);
    }
}

static inline size_t align16(size_t x) { return (x + 15) & ~(size_t)15; }

extern "C" void kernel_launch(void* const* d_in, const int* in_sizes, int n_in,
                              void* d_out, int out_size, void* d_ws, size_t ws_size,
                              hipStream_t stream)
{
    const float* x  = (const float*)d_in[0];
    const float* W0 = (const float*)d_in[1];
    const float* b0 = (const float*)d_in[2];
    const float* W1 = (const float*)d_in[3];
    const float* b1 = (const float*)d_in[4];
    const int* eidx = (const int*)d_in[5];
    const int* etyp = (const int*)d_in[6];

    const int M = in_sizes[0] / DIM;   // 50000
    const int E = in_sizes[6];         // 800000
    const int* src = eidx;
    const int* dst = eidx + E;
    float* out = (float*)d_out;

    const size_t plane = (size_t)M * DIM;
    const size_t wbytes = (size_t)N_REL * DIM * DIM * 2;
    const size_t yall_bytes = (size_t)N_REL * plane * 2;   // 204.8MB

    // Transients (e64a, e64b, hist = 2*E*8 + 1MB ~ 13.8MB) live INSIDE the
    // yall region (R13/R17) -- all dead before the first GEMM writes yall.
    const size_t trans_bytes = 2 * (size_t)E * 8 + (size_t)NBH * NBLK * 4;
    const size_t need = align16(plane * 2)              // h1b
                      + align16(plane * 2)              // xb
                      + 2 * align16(wbytes)             // Wt0b, Wt1b
                      + align16((size_t)(M + 1) * 4)    // rowptr
                      + align16((size_t)M * 4)          // cnt
                      + align16((size_t)256 * 4)        // bsum
                      + align16((size_t)E * 4)          // ep
                      + align16(yall_bytes);            // yall (transient alias)

    if (M < 65536 && ws_size >= need && yall_bytes >= trans_bytes) {
        char* ws = (char*)d_ws;
        size_t off = 0;
        unsigned short* h1b  = (unsigned short*)(ws + off); off = align16(off + plane * 2);
        unsigned short* xb   = (unsigned short*)(ws + off); off = align16(off + plane * 2);
        unsigned short* Wt0b = (unsigned short*)(ws + off); off = align16(off + wbytes);
        unsigned short* Wt1b = (unsigned short*)(ws + off); off = align16(off + wbytes);
        int* rowptr = (int*)(ws + off); off = align16(off + (size_t)(M + 1) * 4);
        int* cnt    = (int*)(ws + off); off = align16(off + (size_t)M * 4);
        int* bsum   = (int*)(ws + off); off = align16(off + (size_t)256 * 4);
        unsigned* ep = (unsigned*)(ws + off); off = align16(off + (size_t)E * 4);
        unsigned short* yall = (unsigned short*)(ws + off);
        unsigned long long* e64a = (unsigned long long*)yall;   // transient
        unsigned long long* e64b = e64a + E;                    // transient
        int* hist = (int*)(e64b + E);                           // transient 1MB

        // --- prep megakernel: cast + 2 transposes
        const int n4 = (int)(plane / 4);
        const int nCast = (n4 + 255) / 256;
        const int nW = 512;                 // 8x8 tiles x 8 rels
        prep_mega<<<nCast + 2 * nW, 256, 0, stream>>>(
            x, xb, n4, W0, Wt0b, W1, Wt1b, nCast, nW);

        // --- atomic-free CSR build: MSD bucket sort by dst (R13, R17-widened)
        build_keys_hist<<<NBLK, 256, 0, stream>>>(src, dst, etyp, E, e64a, hist);
        const int nhist = NBH * NBLK;                      // 262144
        const int nbh = (nhist + 1023) / 1024;             // 256
        scan_g_blocksums<<<nbh, 256, 0, stream>>>(hist, nhist, bsum);
        scan_g_write<<<nbh, 256, 0, stream>>>(hist, nhist, bsum, nbh, hist, (int*)nullptr);
        scatter_pass1<<<NBLK, 256, 0, stream>>>(e64a, E, hist, e64b);
        bucket_sort<<<NBH, 256, 0, stream>>>(e64b, E, hist, ep, cnt, M);
        const int nb = (M + 1023) / 1024;                  // 49
        scan_g_blocksums<<<nb, 256, 0, stream>>>(cnt, M, bsum);
        scan_g_write<<<nb, 256, 0, stream>>>(cnt, M, bsum, nb, rowptr, &rowptr[M]);

        const int Rtiles = (M + 127) / 128;
        const int octets = (Rtiles + 7) / 8;
        const int ggrid = octets * 16 * 8;
        const int npair = (M + 1) / 2;
        const int agrid = (npair * 64 + 255) / 256;   // 1 dst per half-wave

        // layer 1 (gemm overwrites the transient region -- sort complete)
        gemm_mfma_bias_relu<<<ggrid, 256, 0, stream>>>(xb, Wt0b, b0, yall, M, Rtiles);
        aggregate2x<unsigned short><<<agrid, 256, 0, stream>>>(yall, ep, rowptr, h1b, M);
        // layer 2
        gemm_mfma_bias_relu<<<ggrid, 256, 0, stream>>>(h1b, Wt1b, b1, yall, M, Rtiles);
        aggregate2x<float><<<agrid, 256, 0, stream>>>(yall, ep, rowptr, out, M);
    } else {
        // fallback: fp32 per-relation GEMM + atomic scatter
        float* h1 = (float*)d_ws;
        float* y  = (float*)d_ws + plane;
        const dim3 gblk(256), ggrid2((M + 127) / 128, DIM / 128);
        hipMemsetAsync(h1, 0, plane * 4, stream);
        for (int r = 0; r < N_REL; r++) {
            gemm_bias_relu_f32<<<ggrid2, gblk, 0, stream>>>(
                x, W0 + (size_t)r * DIM * DIM, b0, y, M);
            scatter_rel<<<1024, 256, 0, stream>>>(y, src, dst, etyp, r, h1, E);
        }
        hipMemsetAsync(out, 0, plane * 4, stream);
        for (int r = 0; r < N_REL; r++) {
            gemm_bias_relu_f32<<<ggrid2, gblk, 0, stream>>>(
                h1, W1 + (size_t)r * DIM * DIM, b1, y, M);
            scatter_rel<<<1024, 256, 0, stream>>>(y, src, dst, etyp, r, out, E);
        }
    }
}

// Round 14
// 431.741 us; speedup vs baseline: 1.5513x; 1.0735x over previous
//
#include <hip/hip_runtime.h>

#define DIM 256
#define N_REL 8
#define NBLK 1024    // blocks in build/scatter passes (R17: 4x wider)
#define NBH 256      // high-byte bins (dst < 65536)

typedef __attribute__((ext_vector_type(8))) short short8_t;
typedef __attribute__((ext_vector_type(4))) float float4_t;
typedef __attribute__((ext_vector_type(2))) float float2_t;

// ---------------- bf16 helpers (manual, RNE) ----------------
__device__ inline unsigned short f2bf(float f) {
    unsigned u = __float_as_uint(f);
    u += 0x7FFFu + ((u >> 16) & 1u);
    return (unsigned short)(u >> 16);
}
__device__ inline float bf2f(unsigned short h) {
    return __uint_as_float(((unsigned)h) << 16);
}

// ---------------------------------------------------------------------------
// prep megakernel: {cast x->bf16 | transpose W0 | transpose W1}.
// R15 lesson: memory-bound phases need wide grids for TLP.
// ---------------------------------------------------------------------------
__global__ __launch_bounds__(256) void prep_mega(
    const float* __restrict__ x, unsigned short* __restrict__ xb, int n4,
    const float* __restrict__ W0, unsigned short* __restrict__ Wt0,
    const float* __restrict__ W1, unsigned short* __restrict__ Wt1,
    int nCast, int nW)
{
    __shared__ float tile[32][33];
    const int b = blockIdx.x;
    const int t = threadIdx.x;
    if (b < nCast) {
        const int i = b * 256 + t;
        if (i < n4) {
            const float4 v = ((const float4*)x)[i];
            ushort4 o;
            o.x = f2bf(v.x); o.y = f2bf(v.y); o.z = f2bf(v.z); o.w = f2bf(v.w);
            ((ushort4*)xb)[i] = o;
        }
    } else {
        const int wi = b - nCast;
        const float* W = (wi < nW) ? W0 : W1;
        unsigned short* Wt = (wi < nW) ? Wt0 : Wt1;
        const int bb = (wi < nW) ? wi : wi - nW;
        const int rel = bb >> 6;
        const int bx = bb & 7, by = (bb >> 3) & 7;
        const int i0 = bx * 32, o0 = by * 32;
        const int tx = t & 31, ty = t >> 5;          // (32, 8)
        const float* Wr = W + (size_t)rel * DIM * DIM;
        unsigned short* Wtr = Wt + (size_t)rel * DIM * DIM;
#pragma unroll
        for (int j = 0; j < 4; j++)
            tile[ty + 8 * j][tx] = Wr[(size_t)(i0 + ty + 8 * j) * DIM + o0 + tx];
        __syncthreads();
#pragma unroll
        for (int j = 0; j < 4; j++)
            Wtr[(size_t)(o0 + ty + 8 * j) * DIM + i0 + tx] =
                f2bf(tile[tx][ty + 8 * j]);
    }
}

// ---------------------------------------------------------------------------
// Atomic-free CSR build: MSD bucket sort by dst, zero global atomics [R13].
// key u64 = [dst:16 @bit32][et:16 @bit16][src:16 @bit0]; payload (low u32)
// is exactly the ep format (et<<16|src).
// R17: build/scatter at 1024 blocks; hist (1MB) aliases the yall transients.
// ---------------------------------------------------------------------------
__global__ __launch_bounds__(256) void build_keys_hist(
    const int* __restrict__ src, const int* __restrict__ dst,
    const int* __restrict__ et, int E,
    unsigned long long* __restrict__ e0, int* __restrict__ hist)
{
    __shared__ int lh[NBH];
    const int t = threadIdx.x, b = blockIdx.x;
    lh[t] = 0;
    __syncthreads();
    const int chunk = (E + NBLK - 1) / NBLK;
    const int lo = b * chunk, hi = min(lo + chunk, E);
    for (int i = lo + t; i < hi; i += 256) {
        const unsigned d = (unsigned)dst[i];
        e0[i] = ((unsigned long long)d << 32) |
                ((unsigned)((et[i] << 16) | src[i]));
        atomicAdd(&lh[d >> 8], 1);          // LDS atomic (fast, banked)
    }
    __syncthreads();
    hist[t * NBLK + b] = lh[t];
}

// Generic exclusive-scan pair (n <= 262144 -> nb <= 256). outArr may alias a
// (each block reads only its own range before writing it).
__global__ __launch_bounds__(256) void scan_g_blocksums(
    const int* __restrict__ a, int n, int* __restrict__ bsum)
{
    __shared__ int red[256];
    const int t = threadIdx.x;
    const int base = blockIdx.x * 1024 + t * 4;
    int s = 0;
#pragma unroll
    for (int j = 0; j < 4; j++) {
        const int i = base + j;
        if (i < n) s += a[i];
    }
    red[t] = s;
    __syncthreads();
#pragma unroll
    for (int off = 128; off > 0; off >>= 1) {
        if (t < off) red[t] += red[t + off];
        __syncthreads();
    }
    if (t == 0) bsum[blockIdx.x] = red[0];
}

__global__ __launch_bounds__(256) void scan_g_write(
    const int* __restrict__ a, int n, const int* __restrict__ bsum, int nb,
    int* __restrict__ outArr, int* __restrict__ totalSlot)
{
    __shared__ int sb[256];
    __shared__ int sh[256];
    const int t = threadIdx.x;
    sb[t] = (t < nb) ? bsum[t] : 0;
    __syncthreads();
    for (int off = 1; off < 256; off <<= 1) {
        const int v = sb[t] + ((t >= off) ? sb[t - off] : 0);
        __syncthreads();
        sb[t] = v;
        __syncthreads();
    }
    const int run0 = (blockIdx.x == 0) ? 0 : sb[blockIdx.x - 1];
    const int total = sb[nb - 1];

    const int base = blockIdx.x * 1024 + t * 4;
    int v[4];
#pragma unroll
    for (int j = 0; j < 4; j++) {
        const int i = base + j;
        v[j] = (i < n) ? a[i] : 0;
    }
    sh[t] = v[0] + v[1] + v[2] + v[3];
    __syncthreads();
    for (int off = 1; off < 256; off <<= 1) {
        const int add = (t >= off) ? sh[t - off] : 0;
        __syncthreads();
        sh[t] += add;
        __syncthreads();
    }
    int run = run0 + ((t == 0) ? 0 : sh[t - 1]);
#pragma unroll
    for (int j = 0; j < 4; j++) {
        const int i = base + j;
        if (i < n) outArr[i] = run;
        run += v[j];
    }
    if (totalSlot && (int)blockIdx.x == nb - 1 && t == 255) *totalSlot = total;
}

// Pass B: scatter into high-byte buckets. Order within bucket varies
// run-to-run (LDS-atomic rank) -- safe: aggregate sums in fp64 (R11).
__global__ __launch_bounds__(256) void scatter_pass1(
    const unsigned long long* __restrict__ e0, int E,
    const int* __restrict__ histx, unsigned long long* __restrict__ e1)
{
    __shared__ int lbase[NBH];
    __shared__ int lrun[NBH];
    const int t = threadIdx.x, b = blockIdx.x;
    lbase[t] = histx[t * NBLK + b];
    lrun[t] = 0;
    __syncthreads();
    const int chunk = (E + NBLK - 1) / NBLK;
    const int lo = b * chunk, hi = min(lo + chunk, E);
    for (int i = lo + t; i < hi; i += 256) {
        const unsigned long long v = e0[i];
        const int bin = (int)(v >> 40) & 0xFF;
        const int pos = lbase[bin] + atomicAdd(&lrun[bin], 1);
        e1[pos] = v;
    }
}

// Pass C: one block per high-byte bucket; LDS counting sort on dst low byte.
// cnt written UNCONDITIONALLY (R17) -> no cnt memset dispatch.
__global__ __launch_bounds__(256) void bucket_sort(
    const unsigned long long* __restrict__ e1, int E,
    const int* __restrict__ histx,
    unsigned* __restrict__ ep, int* __restrict__ cnt, int M)
{
    __shared__ int lh[256], lincl[256], lexcl[256], lrun[256];
    const int t = threadIdx.x;
    const int h = blockIdx.x;
    const int start = histx[h * NBLK];
    const int end = (h == NBH - 1) ? E : histx[(h + 1) * NBLK];
    lh[t] = 0;
    __syncthreads();
    for (int i = start + t; i < end; i += 256)
        atomicAdd(&lh[(int)(e1[i] >> 32) & 0xFF], 1);
    __syncthreads();
    const int v = lh[t];
    const int d = (h << 8) | t;
    if (d < M) cnt[d] = v;               // unconditional (zeros included)
    if (end <= start) return;            // uniform across block (after cnt)
    lincl[t] = v;
    __syncthreads();
    for (int off = 1; off < 256; off <<= 1) {
        const int add = (t >= off) ? lincl[t - off] : 0;
        __syncthreads();
        lincl[t] += add;
        __syncthreads();
    }
    lexcl[t] = lincl[t] - v;
    lrun[t] = 0;
    __syncthreads();
    for (int i = start + t; i < end; i += 256) {
        const unsigned long long x = e1[i];
        const int low = (int)(x >> 32) & 0xFF;
        const int pos = lexcl[low] + atomicAdd(&lrun[low], 1);
        ep[start + pos] = (unsigned)(x & 0xFFFFFFFFu);
    }
}

// ---------------------------------------------------------------------------
// Yall[rel][M][256] = relu(Xb @ W[rel] + bias).  [R13-verified core]
// Tile 128x128, BK=32, 4 waves of 64x64 (4x4 mfma_f32_16x16x32_bf16).
// global_load_lds width=16, XOR seg swizzle on BOTH sides (rule 21),
// 2-buffer vmcnt(4) schedule, R9 2-round epilogue, PLAIN stores (R16: NT
// stores bypass L2 write-combining -> partial-line HBM writes, 81->109us).
// R18: OFMT template -- layer-1 output stored as fp8 e4m3 via HW
// v_cvt_pk_fp8_f32 (halves WRITE 200->103MB; matched HW decode in the
// aggregate makes the round-trip format-consistent). Layer-2 stays bf16
// (messages O(19): fp8 err would breach the 5.8 absmax budget).
// ---------------------------------------------------------------------------
template <int OFMT>   // 0 = bf16 out, 1 = fp8 out
__global__ __launch_bounds__(256) void gemm_mfma_bias_relu(
    const unsigned short* __restrict__ Xb,    // [M][256]
    const unsigned short* __restrict__ Wtb,   // [R][256out][256in]
    const float* __restrict__ bias,           // [256]
    void* __restrict__ Yall, int M, int Rtiles)
{
    __shared__ __align__(16) short smem[16384];   // 32 KiB, 2 buffers

    const unsigned L = blockIdx.x;
    const int xcd = L & 7;
    const unsigned g = L >> 3;
    const int combo = g & 15;                 // (ntile, rel)
    const int rt = (int)((g >> 4) << 3) | xcd;
    if (rt >= Rtiles) return;
    const int m0 = rt * 128;
    const int n0 = (combo & 1) * 128;
    const int rel = combo >> 1;

    const unsigned short* Wt = Wtb + (size_t)rel * DIM * DIM;
    const int esz = OFMT ? 1 : 2;
    unsigned char* Ybase = (unsigned char*)Yall + (size_t)rel * M * DIM * esz;

    const int t = threadIdx.x;
    const int lane = t & 63;
    const int w = t >> 6;
    const int wr = w & 1, wc = w >> 1;
    const int r = lane & 15, q = lane >> 4;

    const int sl = lane & 3;
    const int rsub = lane >> 2;
    const unsigned short* gA[2];
    const unsigned short* gB[2];
#pragma unroll
    for (int h = 0; h < 2; h++) {
        const int row = h * 64 + w * 16 + rsub;
        const int gseg = sl ^ ((row >> 1) & 3);          // pre-swizzled source
        gA[h] = Xb + (size_t)(m0 + row) * DIM + gseg * 8;
        gB[h] = Wt + (size_t)(n0 + row) * DIM + gseg * 8;
    }

    const int swz = (q ^ ((r >> 1) & 3)) * 8;
    int offA[4], offB[4];
#pragma unroll
    for (int mi = 0; mi < 4; mi++)
        offA[mi] = (wr * 64 + mi * 16 + r) * 32 + swz;
#pragma unroll
    for (int ni = 0; ni < 4; ni++)
        offB[ni] = (wc * 64 + ni * 16 + r) * 32 + swz;

    float4_t acc[4][4];
#pragma unroll
    for (int i = 0; i < 4; i++)
#pragma unroll
        for (int j = 0; j < 4; j++) {
            float4_t z = {0.f, 0.f, 0.f, 0.f};
            acc[i][j] = z;
        }

#define STAGE(ks, bsel)                                                         \
    {                                                                           \
        const int k0_ = (ks) * 32;                                              \
        short* Ad_ = smem + ((bsel) ? 8192 : 0);                                \
        short* Bd_ = Ad_ + 4096;                                                \
        _Pragma("unroll")                                                       \
        for (int h = 0; h < 2; h++) {                                           \
            __builtin_amdgcn_global_load_lds(                                   \
                (const __attribute__((address_space(1))) unsigned int*)(gA[h] + k0_), \
                (__attribute__((address_space(3))) unsigned int*)(Ad_ + h * 2048 + w * 512), \
                16, 0, 0);                                                      \
            __builtin_amdgcn_global_load_lds(                                   \
                (const __attribute__((address_space(1))) unsigned int*)(gB[h] + k0_), \
                (__attribute__((address_space(3))) unsigned int*)(Bd_ + h * 2048 + w * 512), \
                16, 0, 0);                                                      \
        }                                                                       \
    }

    STAGE(0, 0);
#pragma unroll 1
    for (int ks = 0; ks < 8; ks++) {
        const int cur = ks & 1;
        if (ks < 7) {
            STAGE(ks + 1, cur ^ 1);
            asm volatile("s_waitcnt vmcnt(4)" ::: "memory");
        } else {
            asm volatile("s_waitcnt vmcnt(0)" ::: "memory");
        }
        asm volatile("s_barrier" ::: "memory");

        const short* As_b = smem + (cur ? 8192 : 0);
        const short* Bs_b = As_b + 4096;
        short8_t af[4], bf[4];
#pragma unroll
        for (int mi = 0; mi < 4; mi++)
            af[mi] = *(const short8_t*)&As_b[offA[mi]];
#pragma unroll
        for (int ni = 0; ni < 4; ni++)
            bf[ni] = *(const short8_t*)&Bs_b[offB[ni]];
#pragma unroll
        for (int mi = 0; mi < 4; mi++)
#pragma unroll
            for (int ni = 0; ni < 4; ni++)
                acc[mi][ni] = __builtin_amdgcn_mfma_f32_16x16x32_bf16(
                    af[mi], bf[ni], acc[mi][ni], 0, 0, 0);
        asm volatile("s_barrier" ::: "memory");
    }
#undef STAGE

    // ---- epilogue: bias+relu, LDS-staged coalesced stores (2 rounds) ----
    short* St = smem;

    float bv[4];
#pragma unroll
    for (int ni = 0; ni < 4; ni++)
        bv[ni] = bias[n0 + wc * 64 + ni * 16 + r];

#pragma unroll
    for (int mp = 0; mp < 2; mp++) {
#pragma unroll
        for (int s = 0; s < 2; s++) {
#pragma unroll
            for (int ni = 0; ni < 4; ni++) {
#pragma unroll
                for (int e = 0; e < 4; e++) {
                    const int rl = s * 32 + wr * 16 + q * 4 + e;
                    const int col = wc * 64 + ni * 16 + r;
                    St[rl * 136 + col] =
                        f2bf(fmaxf(acc[mp * 2 + s][ni][e] + bv[ni], 0.f));
                }
            }
        }
        __syncthreads();
#pragma unroll
        for (int j = 0; j < 4; j++) {
            const int id = t + 256 * j;
            const int rl2 = id >> 4;
            const int ch = id & 15;
            const int s = rl2 >> 5;
            const int rl = rl2 & 31;
            const int grow = m0 + (rl >> 4) * 64 + (mp * 2 + s) * 16 + (rl & 15);
            const short8_t v = *(const short8_t*)&St[rl2 * 136 + ch * 8];
            if (grow < M) {
                if (OFMT == 0) {
                    *(short8_t*)(Ybase +
                        ((size_t)grow * DIM + n0 + ch * 8) * 2) = v;
                } else {
                    // 8 bf16 -> f32 -> 8 fp8 (HW pack, 2/inst)
                    float f0 = bf2f((unsigned short)v[0]);
                    float f1 = bf2f((unsigned short)v[1]);
                    float f2 = bf2f((unsigned short)v[2]);
                    float f3 = bf2f((unsigned short)v[3]);
                    float f4 = bf2f((unsigned short)v[4]);
                    float f5 = bf2f((unsigned short)v[5]);
                    float f6 = bf2f((unsigned short)v[6]);
                    float f7 = bf2f((unsigned short)v[7]);
                    int lo = 0, hi = 0;
                    lo = __builtin_amdgcn_cvt_pk_fp8_f32(f0, f1, lo, false);
                    lo = __builtin_amdgcn_cvt_pk_fp8_f32(f2, f3, lo, true);
                    hi = __builtin_amdgcn_cvt_pk_fp8_f32(f4, f5, hi, false);
                    hi = __builtin_amdgcn_cvt_pk_fp8_f32(f6, f7, hi, true);
                    int2 o; o.x = lo; o.y = hi;
                    *(int2*)(Ybase + (size_t)grow * DIM + n0 + ch * 8) = o;
                }
            }
        }
        if (mp == 0) __syncthreads();
    }
}

// -------- aggregate: one dst per HALF-WAVE, fp64 accumulators [R13] --------
// fp64 sums are order-independent (~2^-53 rel) -> replay-deterministic under
// run-varying ep order. R18: IFMT=1 reads the fp8 layer-1 yall (8B/lane,
// row = 256B fully coalesced per half-wave) and decodes with the HW
// v_cvt_pk_f32_fp8 (matched to the GEMM's encode -> format-consistent).
template <int IFMT, typename OT>
__global__ __launch_bounds__(256) void aggregate2x(
    const void* __restrict__ yallv,            // [R][M][256] bf16 or fp8
    const unsigned* __restrict__ ep, const int* __restrict__ rowptr,
    OT* __restrict__ out, int M)
{
    const int lane = threadIdx.x & 63;
    const int half = lane >> 5;     // which dst of the pair
    const int cl = lane & 31;       // chunk within message row
    const int wv = (blockIdx.x * blockDim.x + threadIdx.x) >> 6;
    const int nw = (gridDim.x * blockDim.x) >> 6;
    const unsigned char* yb = (const unsigned char*)yallv;
    const size_t plane = (size_t)M * DIM * (IFMT ? 1 : 2);
    const int npair = (M + 1) >> 1;

    for (int pr = wv; pr < npair; pr += nw) {
        const int d = 2 * pr + half;
        const bool live = (d < M);
        double acc[8];
#pragma unroll
        for (int j = 0; j < 8; j++) acc[j] = 0.0;

        int beg = 0, end = 0;
        if (live) { beg = rowptr[d]; end = rowptr[d + 1]; }

        for (int c0 = beg; c0 < end; c0 += 32) {
            const int n = min(32, end - c0);
            const unsigned myep = (c0 + cl < end) ? ep[c0 + cl] : 0u;
            for (int i = 0; i < n; i += 4) {
                if (IFMT == 0) {
                    short8_t u[4];
#pragma unroll
                    for (int j = 0; j < 4; j++) {
                        const unsigned p = __shfl(myep, half * 32 + ((i + j) & 31));
                        u[j] = *(const short8_t*)(
                            yb + (size_t)(p >> 16) * plane +
                            ((size_t)(p & 0xFFFFu) * DIM + cl * 8) * 2);
                    }
#pragma unroll
                    for (int j = 0; j < 4; j++) {
                        if (i + j < n) {
#pragma unroll
                            for (int k = 0; k < 8; k++)
                                acc[k] += (double)bf2f((unsigned short)u[j][k]);
                        }
                    }
                } else {
                    int2 u[4];
#pragma unroll
                    for (int j = 0; j < 4; j++) {
                        const unsigned p = __shfl(myep, half * 32 + ((i + j) & 31));
                        u[j] = *(const int2*)(
                            yb + (size_t)(p >> 16) * plane +
                            (size_t)(p & 0xFFFFu) * DIM + cl * 8);
                    }
#pragma unroll
                    for (int j = 0; j < 4; j++) {
                        if (i + j < n) {
                            const float2_t a0 =
                                __builtin_amdgcn_cvt_pk_f32_fp8(u[j].x, false);
                            const float2_t a1 =
                                __builtin_amdgcn_cvt_pk_f32_fp8(u[j].x, true);
                            const float2_t a2 =
                                __builtin_amdgcn_cvt_pk_f32_fp8(u[j].y, false);
                            const float2_t a3 =
                                __builtin_amdgcn_cvt_pk_f32_fp8(u[j].y, true);
                            acc[0] += (double)a0[0]; acc[1] += (double)a0[1];
                            acc[2] += (double)a1[0]; acc[3] += (double)a1[1];
                            acc[4] += (double)a2[0]; acc[5] += (double)a2[1];
                            acc[6] += (double)a3[0]; acc[7] += (double)a3[1];
                        }
                    }
                }
            }
        }
        if (live) {
            OT* dp = out + (size_t)d * DIM + cl * 8;
            if (sizeof(OT) == 4) {
                *(float4*)((float*)dp) = make_float4(
                    (float)acc[0], (float)acc[1], (float)acc[2], (float)acc[3]);
                *(float4*)((float*)dp + 4) = make_float4(
                    (float)acc[4], (float)acc[5], (float)acc[6], (float)acc[7]);
            } else {
                short8_t v;
#pragma unroll
                for (int j = 0; j < 8; j++) v[j] = (short)f2bf((float)acc[j]);
                *(short8_t*)((unsigned short*)dp) = v;
            }
        }
    }
}

// ---------------- fallback: fp32 vector GEMM + atomic scatter ----------------
__global__ __launch_bounds__(256) void gemm_bias_relu_f32(
    const float* __restrict__ A, const float* __restrict__ B,
    const float* __restrict__ bias, float* __restrict__ Y, int M)
{
    __shared__ float Asf[16][132];
    __shared__ float Bsf[16][128];
    const int t = threadIdx.x;
    const int tx = t & 15, ty = t >> 4;
    const int row0 = blockIdx.x * 128, col0 = blockIdx.y * 128;
    float acc[8][8];
#pragma unroll
    for (int i = 0; i < 8; i++)
#pragma unroll
        for (int j = 0; j < 8; j++) acc[i][j] = 0.f;
    const int arow = t >> 2, akseg = (t & 3) * 4;
    const int bk0 = t >> 5, bcol = (t & 31) * 4;
    for (int k0 = 0; k0 < DIM; k0 += 16) {
#pragma unroll
        for (int h = 0; h < 2; h++) {
            const int row = row0 + arow + h * 64;
            float4 av = (row < M) ? *(const float4*)(A + (size_t)row * DIM + k0 + akseg)
                                  : make_float4(0, 0, 0, 0);
            Asf[akseg + 0][arow + h * 64] = av.x;
            Asf[akseg + 1][arow + h * 64] = av.y;
            Asf[akseg + 2][arow + h * 64] = av.z;
            Asf[akseg + 3][arow + h * 64] = av.w;
        }
#pragma unroll
        for (int h = 0; h < 2; h++) {
            const int krow = bk0 + h * 8;
            *(float4*)&Bsf[krow][bcol] =
                *(const float4*)(B + (size_t)(k0 + krow) * DIM + col0 + bcol);
        }
        __syncthreads();
#pragma unroll
        for (int k = 0; k < 16; k++) {
            float a[8], bvv[8];
            *(float4*)&a[0] = *(const float4*)&Asf[k][ty * 4];
            *(float4*)&a[4] = *(const float4*)&Asf[k][64 + ty * 4];
            *(float4*)&bvv[0] = *(const float4*)&Bsf[k][tx * 4];
            *(float4*)&bvv[4] = *(const float4*)&Bsf[k][64 + tx * 4];
#pragma unroll
            for (int i = 0; i < 8; i++)
#pragma unroll
                for (int j = 0; j < 8; j++) acc[i][j] = fmaf(a[i], bvv[j], acc[i][j]);
        }
        __syncthreads();
    }
#pragma unroll
    for (int im = 0; im < 2; im++)
#pragma unroll
        for (int i = 0; i < 4; i++) {
            const int row = row0 + im * 64 + ty * 4 + i;
            if (row >= M) continue;
#pragma unroll
            for (int jm = 0; jm < 2; jm++) {
                const int col = col0 + jm * 64 + tx * 4;
                const float4 bb = *(const float4*)(bias + col);
                float4 o;
                o.x = fmaxf(acc[im * 4 + i][jm * 4 + 0] + bb.x, 0.f);
                o.y = fmaxf(acc[im * 4 + i][jm * 4 + 1] + bb.y, 0.f);
                o.z = fmaxf(acc[im * 4 + i][jm * 4 + 2] + bb.z, 0.f);
                o.w = fmaxf(acc[im * 4 + i][jm * 4 + 3] + bb.w, 0.f);
                *(float4*)(Y + (size_t)row * DIM + col) = o;
            }
        }
}

__global__ __launch_bounds__(256) void scatter_rel(
    const float* __restrict__ y, const int* __restrict__ src,
    const int* __restrict__ dst, const int* __restrict__ et,
    int rel, float* __restrict__ out, int n_edges)
{
    const int lane = threadIdx.x & 63;
    const int wave = (blockIdx.x * blockDim.x + threadIdx.x) >> 6;
    const int nwaves = (gridDim.x * blockDim.x) >> 6;
    for (int e = wave; e < n_edges; e += nwaves) {
        if (et[e] != rel) continue;
        const float4 v = *(const float4*)(y + (size_t)src[e] * DIM + lane * 4);
        float* o = out + (size_t)dst[e] * DIM + lane * 4;
        atomicAdd(o + 0, v.x);
        atomicAdd(o + 1, v.y);
        atomicAdd(o + 2, v.z);
        atomicAdd(o + 3, v.w);
    }
}

static inline size_t align16(size_t x) { return (x + 15) & ~(size_t)15; }

extern "C" void kernel_launch(void* const* d_in, const int* in_sizes, int n_in,
                              void* d_out, int out_size, void* d_ws, size_t ws_size,
                              hipStream_t stream)
{
    const float* x  = (const float*)d_in[0];
    const float* W0 = (const float*)d_in[1];
    const float* b0 = (const float*)d_in[2];
    const float* W1 = (const float*)d_in[3];
    const float* b1 = (const float*)d_in[4];
    const int* eidx = (const int*)d_in[5];
    const int* etyp = (const int*)d_in[6];

    const int M = in_sizes[0] / DIM;   // 50000
    const int E = in_sizes[6];         // 800000
    const int* src = eidx;
    const int* dst = eidx + E;
    float* out = (float*)d_out;

    const size_t plane = (size_t)M * DIM;
    const size_t wbytes = (size_t)N_REL * DIM * DIM * 2;
    const size_t yall_bytes = (size_t)N_REL * plane * 2;   // 204.8MB (bf16 L2)

    // Transients (e64a, e64b, hist ~ 13.8MB) live INSIDE the yall region
    // (R13/R17) -- all dead before the first GEMM writes yall.
    const size_t trans_bytes = 2 * (size_t)E * 8 + (size_t)NBH * NBLK * 4;
    const size_t need = align16(plane * 2)              // h1b
                      + align16(plane * 2)              // xb
                      + 2 * align16(wbytes)             // Wt0b, Wt1b
                      + align16((size_t)(M + 1) * 4)    // rowptr
                      + align16((size_t)M * 4)          // cnt
                      + align16((size_t)256 * 4)        // bsum
                      + align16((size_t)E * 4)          // ep
                      + align16(yall_bytes);            // yall (transient alias)

    if (M < 65536 && ws_size >= need && yall_bytes >= trans_bytes) {
        char* ws = (char*)d_ws;
        size_t off = 0;
        unsigned short* h1b  = (unsigned short*)(ws + off); off = align16(off + plane * 2);
        unsigned short* xb   = (unsigned short*)(ws + off); off = align16(off + plane * 2);
        unsigned short* Wt0b = (unsigned short*)(ws + off); off = align16(off + wbytes);
        unsigned short* Wt1b = (unsigned short*)(ws + off); off = align16(off + wbytes);
        int* rowptr = (int*)(ws + off); off = align16(off + (size_t)(M + 1) * 4);
        int* cnt    = (int*)(ws + off); off = align16(off + (size_t)M * 4);
        int* bsum   = (int*)(ws + off); off = align16(off + (size_t)256 * 4);
        unsigned* ep = (unsigned*)(ws + off); off = align16(off + (size_t)E * 4);
        unsigned short* yall = (unsigned short*)(ws + off);
        unsigned long long* e64a = (unsigned long long*)yall;   // transient
        unsigned long long* e64b = e64a + E;                    // transient
        int* hist = (int*)(e64b + E);                           // transient 1MB

        // --- prep megakernel: cast + 2 transposes
        const int n4 = (int)(plane / 4);
        const int nCast = (n4 + 255) / 256;
        const int nW = 512;                 // 8x8 tiles x 8 rels
        prep_mega<<<nCast + 2 * nW, 256, 0, stream>>>(
            x, xb, n4, W0, Wt0b, W1, Wt1b, nCast, nW);

        // --- atomic-free CSR build: MSD bucket sort by dst (R13, R17-widened)
        build_keys_hist<<<NBLK, 256, 0, stream>>>(src, dst, etyp, E, e64a, hist);
        const int nhist = NBH * NBLK;                      // 262144
        const int nbh = (nhist + 1023) / 1024;             // 256
        scan_g_blocksums<<<nbh, 256, 0, stream>>>(hist, nhist, bsum);
        scan_g_write<<<nbh, 256, 0, stream>>>(hist, nhist, bsum, nbh, hist, (int*)nullptr);
        scatter_pass1<<<NBLK, 256, 0, stream>>>(e64a, E, hist, e64b);
        bucket_sort<<<NBH, 256, 0, stream>>>(e64b, E, hist, ep, cnt, M);
        const int nb = (M + 1023) / 1024;                  // 49
        scan_g_blocksums<<<nb, 256, 0, stream>>>(cnt, M, bsum);
        scan_g_write<<<nb, 256, 0, stream>>>(cnt, M, bsum, nb, rowptr, &rowptr[M]);

        const int Rtiles = (M + 127) / 128;
        const int octets = (Rtiles + 7) / 8;
        const int ggrid = octets * 16 * 8;
        const int npair = (M + 1) / 2;
        const int agrid = (npair * 64 + 255) / 256;   // 1 dst per half-wave

        // layer 1: fp8 message tensor (R18 -- halves GEMM write + agg read)
        gemm_mfma_bias_relu<1><<<ggrid, 256, 0, stream>>>(
            xb, Wt0b, b0, (void*)yall, M, Rtiles);
        aggregate2x<1, unsigned short><<<agrid, 256, 0, stream>>>(
            (const void*)yall, ep, rowptr, h1b, M);
        // layer 2: bf16 (message magnitudes O(19) -- fp8 would breach absmax)
        gemm_mfma_bias_relu<0><<<ggrid, 256, 0, stream>>>(
            h1b, Wt1b, b1, (void*)yall, M, Rtiles);
        aggregate2x<0, float><<<agrid, 256, 0, stream>>>(
            (const void*)yall, ep, rowptr, out, M);
    } else {
        // fallback: fp32 per-relation GEMM + atomic scatter
        float* h1 = (float*)d_ws;
        float* y  = (float*)d_ws + plane;
        const dim3 gblk(256), ggrid2((M + 127) / 128, DIM / 128);
        hipMemsetAsync(h1, 0, plane * 4, stream);
        for (int r = 0; r < N_REL; r++) {
            gemm_bias_relu_f32<<<ggrid2, gblk, 0, stream>>>(
                x, W0 + (size_t)r * DIM * DIM, b0, y, M);
            scatter_rel<<<1024, 256, 0, stream>>>(y, src, dst, etyp, r, h1, E);
        }
        hipMemsetAsync(out, 0, plane * 4, stream);
        for (int r = 0; r < N_REL; r++) {
            gemm_bias_relu_f32<<<ggrid2, gblk, 0, stream>>>(
                h1, W1 + (size_t)r * DIM * DIM, b1, y, M);
            scatter_rel<<<1024, 256, 0, stream>>>(y, src, dst, etyp, r, out, E);
        }
    }
}